// Round 11
// baseline (1252.135 us; speedup 1.0000x reference)
//
#include <hip/hip_runtime.h>
#include <hip/hip_fp16.h>
#include <math.h>

#define N_NODES 30000
#define N_EDGES 480000
#define N_EDGES_SL (N_EDGES + N_NODES)
#define DIM_IN 256
#define F1 512   // HEADS*HID
#define HEADS 8
#define NGRAPH 512
#define NEG 0.2f
#define MB_TILES 235  // ceil(30000/128)
#define N_OCT 3750    // N_NODES/8

typedef __attribute__((ext_vector_type(8))) short short8;
typedef __attribute__((ext_vector_type(4))) float f32x4;

__device__ __forceinline__ float lrelu(float x) { return fmaxf(x, NEG * x); }  // NEG in (0,1)
__device__ __forceinline__ float elu_(float x) { return x > 0.f ? x : __expf(x) - 1.f; }

// split fp32 -> bf16 hi + bf16 lo (round-to-nearest-even both)
__device__ __forceinline__ void cvt_split(float a, unsigned short& h, unsigned short& l) {
    unsigned u = __float_as_uint(a);
    unsigned hb = (u + 0x7fffu + ((u >> 16) & 1u)) >> 16;
    h = (unsigned short)hb;
    float res = a - __uint_as_float(hb << 16);
    unsigned v = __float_as_uint(res);
    l = (unsigned short)((v + 0x7fffu + ((v >> 16) & 1u)) >> 16);
}

// async global->LDS, 16B per lane
__device__ __forceinline__ void glds16(const unsigned short* g, unsigned short* l) {
    __builtin_amdgcn_global_load_lds(
        (const __attribute__((address_space(1))) unsigned int*)g,
        (__attribute__((address_space(3))) unsigned int*)l, 16, 0, 0);
}

// ---------------- CSR build ----------------
__global__ void k_count(const int* __restrict__ ei, int* __restrict__ deg) {
    int i = blockIdx.x * blockDim.x + threadIdx.x;
    if (i < N_EDGES) atomicAdd(&deg[ei[N_EDGES + i]], 1);
}

// single-block 1024-thread scan (replaces 3-phase; 16 waves hide load latency)
__global__ __launch_bounds__(1024) void k_scan2(const int* __restrict__ deg,
                                                int* __restrict__ offs,
                                                int* __restrict__ cursor) {
    const int t = threadIdx.x;
    int lo = t * 30;                        // 1024*30 = 30720 >= 30000
    int hi = min(lo + 30, N_NODES);
    int s = 0;
    for (int i = lo; i < hi; ++i) s += deg[i] + 1;  // +1: self-loop
    __shared__ int p[1024];
    p[t] = s;
    __syncthreads();
    for (int off = 1; off < 1024; off <<= 1) {
        int v = (t >= off) ? p[t - off] : 0;
        __syncthreads();
        p[t] += v;
        __syncthreads();
    }
    int run = p[t] - s;  // exclusive
    for (int i = lo; i < hi; ++i) {
        int d = deg[i];  // read BEFORE cursor write (cursor aliases deg)
        offs[i] = run;
        cursor[i] = run;
        run += d + 1;
    }
    if (t == 1023) offs[N_NODES] = p[1023];
}

__global__ void k_scatter(const int* __restrict__ ei, int* __restrict__ cursor,
                          int* __restrict__ csrc) {
    int i = blockIdx.x * blockDim.x + threadIdx.x;
    if (i >= N_EDGES_SL) return;
    int s, d;
    if (i < N_EDGES) { s = ei[i]; d = ei[N_EDGES + i]; }
    else { s = d = i - N_EDGES; }
    int p = atomicAdd(&cursor[d], 1);
    csrc[p] = s;
}

// ---------------- merged pack + bounds + wq-zero (all depend only on inputs) -------
__device__ __forceinline__ void d_packA(int t, const float* __restrict__ A,
                                        unsigned short* __restrict__ hi,
                                        unsigned short* __restrict__ lo,
                                        int M, int K) {
    int KB = K >> 5;
    int k8 = t & 3;
    int ml = (t >> 2) & 127;
    int tmp = t >> 9;
    int kb = tmp % KB;
    int mb = tmp / KB;
    int m = mb * 128 + ml;
    int k0 = kb * 32 + k8 * 8;
    float v[8] = {0.f, 0.f, 0.f, 0.f, 0.f, 0.f, 0.f, 0.f};
    if (m < M) {
        float4 p0 = *(const float4*)(A + (size_t)m * K + k0);
        float4 p1 = *(const float4*)(A + (size_t)m * K + k0 + 4);
        v[0] = p0.x; v[1] = p0.y; v[2] = p0.z; v[3] = p0.w;
        v[4] = p1.x; v[5] = p1.y; v[6] = p1.z; v[7] = p1.w;
    }
    unsigned short h[8], l[8];
#pragma unroll
    for (int j = 0; j < 8; ++j) cvt_split(v[j], h[j], l[j]);
    size_t o = (size_t)t * 8;
    *(short8*)(hi + o) = *(short8*)h;
    *(short8*)(lo + o) = *(short8*)l;
}

__device__ __forceinline__ void d_packW(int t, const float* __restrict__ W,
                                        unsigned short* __restrict__ hi,
                                        unsigned short* __restrict__ lo,
                                        int K, int Nn, int BN, int LB) {
    int KB = K >> 5;
    int k8 = t & 3;
    int tmp = t >> 2;
    int nl = tmp & (BN - 1);
    int tmp2 = tmp >> LB;
    int kb = tmp2 % KB;
    int nb = tmp2 / KB;
    int n = nb * BN + nl;
    int k0 = kb * 32 + k8 * 8;
    unsigned short h[8], l[8];
#pragma unroll
    for (int j = 0; j < 8; ++j) cvt_split(W[(size_t)(k0 + j) * Nn + n], h[j], l[j]);
    size_t o = (size_t)t * 8;
    *(short8*)(hi + o) = *(short8*)h;
    *(short8*)(lo + o) = *(short8*)l;
}

#define PB_A 3760
#define PB_W1 64
#define PB_W2 128
#define PB_W3 16
__global__ __launch_bounds__(256) void k_packall(
        const float* __restrict__ x, const float* __restrict__ W1,
        const float* __restrict__ W2, const float* __restrict__ W3,
        const int* __restrict__ batch,
        unsigned short* __restrict__ Ah, unsigned short* __restrict__ Al,
        unsigned short* __restrict__ Wh1, unsigned short* __restrict__ Wl1,
        unsigned short* __restrict__ Wh2, unsigned short* __restrict__ Wl2,
        unsigned short* __restrict__ Wh3, unsigned short* __restrict__ Wl3,
        int* __restrict__ gstart, int* __restrict__ wq) {
    int b = blockIdx.x, tid = threadIdx.x;
    if (b < PB_A) {
        d_packA(b * 256 + tid, x, Ah, Al, N_NODES, DIM_IN);
    } else if (b < PB_A + PB_W1) {
        d_packW((b - PB_A) * 256 + tid, W1, Wh1, Wl1, DIM_IN, F1, 128, 7);
    } else if (b < PB_A + PB_W1 + PB_W2) {
        d_packW((b - PB_A - PB_W1) * 256 + tid, W2, Wh2, Wl2, F1, F1, 128, 7);
    } else if (b < PB_A + PB_W1 + PB_W2 + PB_W3) {
        d_packW((b - PB_A - PB_W1 - PB_W2) * 256 + tid, W3, Wh3, Wl3, F1, 64, 64, 6);
    } else {
        int bb = b - (PB_A + PB_W1 + PB_W2 + PB_W3);
        int i = bb * 256 + tid;
        if (bb == 0 && tid < 16) wq[tid] = 0;  // agg8 work queues (conv1: 0-7, conv2: 8-15)
        if (i >= N_NODES) return;
        int bt = batch[i];
        int pb = (i == 0) ? -1 : batch[i - 1];
        for (int g = pb + 1; g <= bt; ++g) gstart[g] = i;
        if (i == N_NODES - 1)
            for (int g = bt + 1; g <= NGRAPH; ++g) gstart[g] = N_NODES;
    }
}
#define PACKALL_BLOCKS (PB_A + PB_W1 + PB_W2 + PB_W3 + 118)

// ---------------- split-bf16 MFMA GEMM, 8-head conv (Nn=512, BN=128, NF=4) ----------
// Fused epilogue: H fp16 head-split [head][node][64]; alphas head-split [head][node].
template <int KB>
__global__ __launch_bounds__(256) void k_gemm8(const unsigned short* __restrict__ Ah,
                                               const unsigned short* __restrict__ Al,
                                               const unsigned short* __restrict__ Bh,
                                               const unsigned short* __restrict__ Bl,
                                               const float* __restrict__ a_src,
                                               const float* __restrict__ a_dst,
                                               __half* __restrict__ Hf,
                                               float* __restrict__ as_,
                                               float* __restrict__ ad_,
                                               int M) {
    __shared__ unsigned short sAh[4096], sAl[4096], sBh[4096], sBl[4096];
    const int tid = threadIdx.x, lane = tid & 63, wave = tid >> 6;
    const int mb = blockIdx.x, nb = blockIdx.y;
    const int wm = (wave >> 1) * 64;
    const int wn = (wave & 1) * 64;
    const int fr = lane & 15, quad = lane >> 4;

    const unsigned short* pAh = Ah + (size_t)mb * KB * 4096;
    const unsigned short* pAl = Al + (size_t)mb * KB * 4096;
    const unsigned short* pBh = Bh + (size_t)nb * KB * 4096;
    const unsigned short* pBl = Bl + (size_t)nb * KB * 4096;

    f32x4 acc[4][4];
#pragma unroll
    for (int i = 0; i < 4; ++i)
#pragma unroll
        for (int j = 0; j < 4; ++j) acc[i][j] = {0.f, 0.f, 0.f, 0.f};

    for (int kb = 0; kb < KB; ++kb) {
        const unsigned short* ah_g = pAh + kb * 4096;
        const unsigned short* al_g = pAl + kb * 4096;
        const unsigned short* bh_g = pBh + kb * 4096;
        const unsigned short* bl_g = pBl + kb * 4096;
#pragma unroll
        for (int s = 0; s < 2; ++s) {
            int sg = wave * 2 + s;
            glds16(ah_g + sg * 512 + lane * 8, &sAh[sg * 512]);
            glds16(al_g + sg * 512 + lane * 8, &sAl[sg * 512]);
            glds16(bh_g + sg * 512 + lane * 8, &sBh[sg * 512]);
            glds16(bl_g + sg * 512 + lane * 8, &sBl[sg * 512]);
        }
        __syncthreads();

        short8 af_h[4], af_l[4], bf_h[4], bf_l[4];
#pragma unroll
        for (int f = 0; f < 4; ++f) {
            int m = wm + f * 16 + fr;
            af_h[f] = *(const short8*)&sAh[m * 32 + quad * 8];
            af_l[f] = *(const short8*)&sAl[m * 32 + quad * 8];
            int n = wn + f * 16 + fr;
            bf_h[f] = *(const short8*)&sBh[n * 32 + quad * 8];
            bf_l[f] = *(const short8*)&sBl[n * 32 + quad * 8];
        }
#pragma unroll
        for (int i = 0; i < 4; ++i)
#pragma unroll
            for (int j = 0; j < 4; ++j) {
                acc[i][j] = __builtin_amdgcn_mfma_f32_16x16x32_bf16(af_h[i], bf_h[j], acc[i][j], 0, 0, 0);
                acc[i][j] = __builtin_amdgcn_mfma_f32_16x16x32_bf16(af_h[i], bf_l[j], acc[i][j], 0, 0, 0);
                acc[i][j] = __builtin_amdgcn_mfma_f32_16x16x32_bf16(af_l[i], bf_h[j], acc[i][j], 0, 0, 0);
            }
        __syncthreads();
    }
    // epilogue; C/D layout: col=lane&15, row=quad*4+reg
    const int head = (nb * 128 + wn) >> 6;  // wave's 64 cols = one head
    float avs[4], avd[4];
#pragma unroll
    for (int j = 0; j < 4; ++j) {
        avs[j] = a_src[head * 64 + j * 16 + fr];
        avd[j] = a_dst[head * 64 + j * 16 + fr];
    }
    __half* Hh = Hf + (size_t)head * N_NODES * 64;
#pragma unroll
    for (int i = 0; i < 4; ++i) {
#pragma unroll
        for (int r = 0; r < 4; ++r) {
            int row = mb * 128 + wm + i * 16 + quad * 4 + r;
            bool ok = row < M;
            float vs = 0.f, vd = 0.f;
#pragma unroll
            for (int j = 0; j < 4; ++j) {
                float c = acc[i][j][r];
                vs = fmaf(c, avs[j], vs);
                vd = fmaf(c, avd[j], vd);
                if (ok) Hh[(size_t)row * 64 + j * 16 + fr] = __float2half(c);
            }
#pragma unroll
            for (int off = 1; off < 16; off <<= 1) {
                vs += __shfl_xor(vs, off);
                vd += __shfl_xor(vd, off);
            }
            if (ok && fr == 0) {
                as_[head * N_NODES + row] = vs;
                ad_[head * N_NODES + row] = vd;
            }
        }
    }
}

// ---------------- split-bf16 MFMA GEMM, fp16 out (conv3: Nn=64) ----------
template <int KB, int NF>
__global__ __launch_bounds__(256) void k_gemm_mfma(const unsigned short* __restrict__ Ah,
                                                   const unsigned short* __restrict__ Al,
                                                   const unsigned short* __restrict__ Bh,
                                                   const unsigned short* __restrict__ Bl,
                                                   __half* __restrict__ C,
                                                   int M, int Nn) {
    constexpr int BN = NF * 32;
    constexpr int SBW = BN / 64;
    __shared__ unsigned short sAh[4096], sAl[4096], sBh[BN * 32], sBl[BN * 32];
    const int tid = threadIdx.x, lane = tid & 63, wave = tid >> 6;
    const int mb = blockIdx.x, nb = blockIdx.y;
    const int wm = (wave >> 1) * 64;
    const int wn = (wave & 1) * (BN / 2);
    const int fr = lane & 15, quad = lane >> 4;

    const unsigned short* pAh = Ah + (size_t)mb * KB * 4096;
    const unsigned short* pAl = Al + (size_t)mb * KB * 4096;
    const unsigned short* pBh = Bh + (size_t)nb * KB * (BN * 32);
    const unsigned short* pBl = Bl + (size_t)nb * KB * (BN * 32);

    f32x4 acc[4][NF];
#pragma unroll
    for (int i = 0; i < 4; ++i)
#pragma unroll
        for (int j = 0; j < NF; ++j) acc[i][j] = {0.f, 0.f, 0.f, 0.f};

    for (int kb = 0; kb < KB; ++kb) {
        const unsigned short* ah_g = pAh + kb * 4096;
        const unsigned short* al_g = pAl + kb * 4096;
        const unsigned short* bh_g = pBh + kb * (BN * 32);
        const unsigned short* bl_g = pBl + kb * (BN * 32);
#pragma unroll
        for (int s = 0; s < 2; ++s) {
            int sg = wave * 2 + s;
            glds16(ah_g + sg * 512 + lane * 8, &sAh[sg * 512]);
            glds16(al_g + sg * 512 + lane * 8, &sAl[sg * 512]);
        }
#pragma unroll
        for (int s = 0; s < SBW; ++s) {
            int sg = wave * SBW + s;
            glds16(bh_g + sg * 512 + lane * 8, &sBh[sg * 512]);
            glds16(bl_g + sg * 512 + lane * 8, &sBl[sg * 512]);
        }
        __syncthreads();

        short8 af_h[4], af_l[4], bf_h[NF], bf_l[NF];
#pragma unroll
        for (int f = 0; f < 4; ++f) {
            int m = wm + f * 16 + fr;
            af_h[f] = *(const short8*)&sAh[m * 32 + quad * 8];
            af_l[f] = *(const short8*)&sAl[m * 32 + quad * 8];
        }
#pragma unroll
        for (int f = 0; f < NF; ++f) {
            int n = wn + f * 16 + fr;
            bf_h[f] = *(const short8*)&sBh[n * 32 + quad * 8];
            bf_l[f] = *(const short8*)&sBl[n * 32 + quad * 8];
        }
#pragma unroll
        for (int i = 0; i < 4; ++i)
#pragma unroll
            for (int j = 0; j < NF; ++j) {
                acc[i][j] = __builtin_amdgcn_mfma_f32_16x16x32_bf16(af_h[i], bf_h[j], acc[i][j], 0, 0, 0);
                acc[i][j] = __builtin_amdgcn_mfma_f32_16x16x32_bf16(af_h[i], bf_l[j], acc[i][j], 0, 0, 0);
                acc[i][j] = __builtin_amdgcn_mfma_f32_16x16x32_bf16(af_l[i], bf_h[j], acc[i][j], 0, 0, 0);
            }
        __syncthreads();
    }
#pragma unroll
    for (int i = 0; i < 4; ++i) {
#pragma unroll
        for (int r = 0; r < 4; ++r) {
            int row = mb * 128 + wm + i * 16 + quad * 4 + r;
            if (row < M) {
#pragma unroll
                for (int j = 0; j < NF; ++j)
                    C[(size_t)row * Nn + nb * BN + wn + j * 16 + fr] =
                        __float2half(acc[i][j][r]);
            }
        }
    }
}

// process one gathered edge: w*H[src] into 8-channel accumulator (v_fma_mix path)
__device__ __forceinline__ void edge_fma(float w, uint4 u, float* a) {
    const _Float16* hp = (const _Float16*)&u;
#pragma unroll
    for (int k = 0; k < 8; ++k) a[k] = fmaf(w, (float)hp[k], a[k]);
}

// ---------------- softmax-aggregate (8 heads), head-split, XCD-affine --------------
// One wave = 8 dsts x 1 head; lane owns (dst = lane>>3, 8 ch = lane&7). Single pass,
// inline exp. Dynamic per-head octet queue (load balance). Unsigned 32-bit gather
// offsets. head = blockIdx&7 pins head to XCD (2048 co-resident blocks).
__global__ __launch_bounds__(256) void k_agg8(const __half* __restrict__ Hf,
                                              const float* __restrict__ as_,
                                              const float* __restrict__ ad_,
                                              const int* __restrict__ offs,
                                              const int* __restrict__ csrc,
                                              const float* __restrict__ bias,
                                              unsigned short* __restrict__ outh,
                                              unsigned short* __restrict__ outl,
                                              int* __restrict__ wq) {
    const int head = blockIdx.x & 7;
    const int lane = threadIdx.x & 63;
    const int g = lane >> 3, cl = lane & 7;
    const unsigned coff = (unsigned)(cl * 8);
    const __half* Hh = Hf + (size_t)head * N_NODES * 64;
    const float* ash = as_ + head * N_NODES;
    const float* adh = ad_ + head * N_NODES;
    float bia[8];
#pragma unroll
    for (int j = 0; j < 8; ++j) bia[j] = bias[head * 64 + cl * 8 + j];
    int* q = wq + head;

    for (;;) {
        int oct;
        if (lane == 0) oct = atomicAdd(q, 1);
        oct = __shfl(oct, 0);
        if (oct >= N_OCT) break;
        int dst = oct * 8 + g;
        int beg = offs[dst], end = offs[dst + 1];
        float adv = adh[dst];
        const int* cp = csrc + beg;
        int deg = end - beg;
        float s = 0.f;
        float a[8] = {0.f, 0.f, 0.f, 0.f, 0.f, 0.f, 0.f, 0.f};
        float b[8] = {0.f, 0.f, 0.f, 0.f, 0.f, 0.f, 0.f, 0.f};
        int loc = 0;
        for (; loc + 3 < deg; loc += 4) {
            unsigned s0 = (unsigned)cp[loc], s1 = (unsigned)cp[loc + 1];
            unsigned s2 = (unsigned)cp[loc + 2], s3 = (unsigned)cp[loc + 3];
            float e0 = ash[s0], e1 = ash[s1], e2 = ash[s2], e3 = ash[s3];
            uint4 u0 = *(const uint4*)(Hh + s0 * 64u + coff);
            uint4 u1 = *(const uint4*)(Hh + s1 * 64u + coff);
            uint4 u2 = *(const uint4*)(Hh + s2 * 64u + coff);
            uint4 u3 = *(const uint4*)(Hh + s3 * 64u + coff);
            float w0 = __expf(lrelu(e0 + adv));
            float w1 = __expf(lrelu(e1 + adv));
            float w2 = __expf(lrelu(e2 + adv));
            float w3 = __expf(lrelu(e3 + adv));
            s += (w0 + w1) + (w2 + w3);
            edge_fma(w0, u0, a);
            edge_fma(w1, u1, b);
            edge_fma(w2, u2, a);
            edge_fma(w3, u3, b);
        }
        for (; loc < deg; ++loc) {
            unsigned s0 = (unsigned)cp[loc];
            float w = __expf(lrelu(ash[s0] + adv));
            uint4 u = *(const uint4*)(Hh + s0 * 64u + coff);
            s += w;
            edge_fma(w, u, a);
        }
        float inv = 1.f / s;
        float o[8];
#pragma unroll
        for (int k = 0; k < 8; ++k) o[k] = elu_((a[k] + b[k]) * inv + bia[k]);
        unsigned short h[8], l[8];
#pragma unroll
        for (int k = 0; k < 8; ++k) cvt_split(o[k], h[k], l[k]);
        // packed A-tile write: global ch c0 = head*64 + cl*8
        int c0 = head * 64 + cl * 8;
        int kb = c0 >> 5, kl = c0 & 31;
        int mb = dst >> 7, ml = dst & 127;
        size_t oo = (((size_t)(mb * 16 + kb) * 128 + ml) * 32 + kl);
        *(short8*)(outh + oo) = *(short8*)h;
        *(short8*)(outl + oo) = *(short8*)l;
    }
}

// ---------------- conv3: 1 head x 64 ch ----------------
__global__ __launch_bounds__(256) void k_alphas1(const __half* __restrict__ H,
                                                 const float* __restrict__ a_src,
                                                 const float* __restrict__ a_dst,
                                                 float* __restrict__ as_,
                                                 float* __restrict__ ad_) {
    int wid = blockIdx.x * 4 + (threadIdx.x >> 6);
    int lane = threadIdx.x & 63;
    if (wid >= N_NODES) return;
    float h = __half2float(H[(size_t)wid * 64 + lane]);
    float ps = h * a_src[lane];
    float pd = h * a_dst[lane];
#pragma unroll
    for (int off = 1; off < 64; off <<= 1) {
        ps += __shfl_xor(ps, off);
        pd += __shfl_xor(pd, off);
    }
    if (lane == 0) { as_[wid] = ps; ad_[wid] = pd; }
}

// single-pass, 4-deep pipeline; writes h3 [node][64] fp32
__global__ __launch_bounds__(256) void k_agg1(const __half* __restrict__ Hf,
                                              const float* __restrict__ as_,
                                              const float* __restrict__ ad_,
                                              const int* __restrict__ offs,
                                              const int* __restrict__ csrc,
                                              const float* __restrict__ bias,
                                              float* __restrict__ h3) {
    const int wave = threadIdx.x >> 6, lane = threadIdx.x & 63;
    const int g = lane >> 3, cl = lane & 7;
    const unsigned coff = (unsigned)(cl * 8);
    int d0 = (blockIdx.x * 4 + wave) * 8;  // grid 940 -> 3760 octets >= 3750
    if (d0 >= N_NODES) return;
    int dst = d0 + g;
    float bia[8];
#pragma unroll
    for (int j = 0; j < 8; ++j) bia[j] = bias[cl * 8 + j];
    int beg = offs[dst], end = offs[dst + 1];
    float adv = ad_[dst];
    const int* cp = csrc + beg;
    int deg = end - beg;
    float s = 0.f;
    float a[8] = {0.f, 0.f, 0.f, 0.f, 0.f, 0.f, 0.f, 0.f};
    float b[8] = {0.f, 0.f, 0.f, 0.f, 0.f, 0.f, 0.f, 0.f};
    int loc = 0;
    for (; loc + 3 < deg; loc += 4) {
        unsigned s0 = (unsigned)cp[loc], s1 = (unsigned)cp[loc + 1];
        unsigned s2 = (unsigned)cp[loc + 2], s3 = (unsigned)cp[loc + 3];
        float e0 = as_[s0], e1 = as_[s1], e2 = as_[s2], e3 = as_[s3];
        uint4 u0 = *(const uint4*)(Hf + s0 * 64u + coff);
        uint4 u1 = *(const uint4*)(Hf + s1 * 64u + coff);
        uint4 u2 = *(const uint4*)(Hf + s2 * 64u + coff);
        uint4 u3 = *(const uint4*)(Hf + s3 * 64u + coff);
        float w0 = __expf(lrelu(e0 + adv));
        float w1 = __expf(lrelu(e1 + adv));
        float w2 = __expf(lrelu(e2 + adv));
        float w3 = __expf(lrelu(e3 + adv));
        s += (w0 + w1) + (w2 + w3);
        edge_fma(w0, u0, a);
        edge_fma(w1, u1, b);
        edge_fma(w2, u2, a);
        edge_fma(w3, u3, b);
    }
    for (; loc < deg; ++loc) {
        unsigned s0 = (unsigned)cp[loc];
        float w = __expf(lrelu(as_[s0] + adv));
        uint4 u = *(const uint4*)(Hf + s0 * 64u + coff);
        s += w;
        edge_fma(w, u, a);
    }
    float inv = 1.f / s;
    float o[8];
#pragma unroll
    for (int k = 0; k < 8; ++k) o[k] = elu_((a[k] + b[k]) * inv + bia[k]);
    float* op = h3 + (size_t)dst * 64 + cl * 8;
    *(float4*)op = make_float4(o[0], o[1], o[2], o[3]);
    *(float4*)(op + 4) = make_float4(o[4], o[5], o[6], o[7]);
}

// ---------------- segmented mean-pool (sorted batch) + fc, no atomics ----------
__global__ __launch_bounds__(128) void k_poolfc(const float* __restrict__ h3,
                                                const int* __restrict__ gstart,
                                                const float* __restrict__ W,
                                                const float* __restrict__ b,
                                                float* __restrict__ out) {
    int g = blockIdx.x;
    int t = threadIdx.x;  // 128
    int s0 = gstart[g], s1 = gstart[g + 1];
    int c = t & 63, half = t >> 6;
    float acc = 0.f;
    for (int r = s0 + half; r < s1; r += 2) acc += h3[(size_t)r * 64 + c];
    __shared__ float p2[128];
    __shared__ float p[64];
    p2[t] = acc;
    __syncthreads();
    if (t < 64) {
        float cntf = (float)(s1 - s0);
        p[t] = (p2[t] + p2[t + 64]) / fmaxf(cntf, 1.f);
    }
    __syncthreads();
    float o = b[t];
#pragma unroll
    for (int k = 0; k < 64; ++k) o = fmaf(p[k], W[k * 128 + t], o);
    out[g * 128 + t] = o;
}

extern "C" void kernel_launch(void* const* d_in, const int* in_sizes, int n_in,
                              void* d_out, int out_size, void* d_ws, size_t ws_size,
                              hipStream_t stream) {
    const float* x     = (const float*)d_in[0];
    const int*   ei    = (const int*)d_in[1];
    const int*   batch = (const int*)d_in[2];
    const float* W1    = (const float*)d_in[3];
    const float* as1   = (const float*)d_in[4];
    const float* ad1   = (const float*)d_in[5];
    const float* b1    = (const float*)d_in[6];
    const float* W2    = (const float*)d_in[7];
    const float* as2   = (const float*)d_in[8];
    const float* ad2   = (const float*)d_in[9];
    const float* b2    = (const float*)d_in[10];
    const float* W3    = (const float*)d_in[11];
    const float* as3   = (const float*)d_in[12];
    const float* ad3   = (const float*)d_in[13];
    const float* b3    = (const float*)d_in[14];
    const float* Wfc   = (const float*)d_in[15];
    const float* bfc   = (const float*)d_in[16];
    float* out = (float*)d_out;

    char* ws = (char*)d_ws;
    size_t off = 0;
    auto alloc = [&](size_t bytes) -> void* {
        void* p = ws + off;
        off += (bytes + 255) & ~(size_t)255;
        return p;
    };
    __half* Hf = (__half*)alloc((size_t)HEADS * N_NODES * 64 * 2);  // [head][node][64]
    __half* Hf3 = (__half*)alloc((size_t)N_NODES * 64 * 2);
    float* h3 = (float*)alloc((size_t)N_NODES * 64 * 4);
    unsigned short* Ah = (unsigned short*)alloc((size_t)MB_TILES * 16 * 4096 * 2);
    unsigned short* Al = (unsigned short*)alloc((size_t)MB_TILES * 16 * 4096 * 2);
    unsigned short* Wh1 = (unsigned short*)alloc((size_t)131072 * 2);
    unsigned short* Wl1 = (unsigned short*)alloc((size_t)131072 * 2);
    unsigned short* Wh2 = (unsigned short*)alloc((size_t)262144 * 2);
    unsigned short* Wl2 = (unsigned short*)alloc((size_t)262144 * 2);
    unsigned short* Wh3 = (unsigned short*)alloc((size_t)32768 * 2);
    unsigned short* Wl3 = (unsigned short*)alloc((size_t)32768 * 2);
    float* asb   = (float*)alloc((size_t)HEADS * N_NODES * 4);  // [head][node]
    float* adb   = (float*)alloc((size_t)HEADS * N_NODES * 4);
    int*   offs  = (int*)alloc((N_NODES + 1) * 4);
    int*   deg   = (int*)alloc(N_NODES * 4);   // reused as scatter cursor
    int*   csrc  = (int*)alloc((size_t)N_EDGES_SL * 4);
    int*   gstart= (int*)alloc((NGRAPH + 1) * 4);
    int*   wq    = (int*)alloc(16 * 4);

    hipMemsetAsync(deg, 0, N_NODES * 4, stream);

    // pack everything + graph bounds + zero work queues (depends only on inputs)
    k_packall<<<PACKALL_BLOCKS, 256, 0, stream>>>(x, W1, W2, W3, batch, Ah, Al,
                                                  Wh1, Wl1, Wh2, Wl2, Wh3, Wl3,
                                                  gstart, wq);
    // CSR build
    k_count<<<(N_EDGES + 255) / 256, 256, 0, stream>>>(ei, deg);
    k_scan2<<<1, 1024, 0, stream>>>(deg, offs, deg);
    k_scatter<<<(N_EDGES_SL + 255) / 256, 256, 0, stream>>>(ei, deg, csrc);

    // ---- conv1: K=256 (KB=8) ----
    k_gemm8<8><<<dim3(MB_TILES, 4), 256, 0, stream>>>(Ah, Al, Wh1, Wl1, as1, ad1, Hf, asb, adb, N_NODES);
    k_agg8<<<2048, 256, 0, stream>>>(Hf, asb, adb, offs, csrc, b1, Ah, Al, wq);

    // ---- conv2: K=512 (KB=16) ----
    k_gemm8<16><<<dim3(MB_TILES, 4), 256, 0, stream>>>(Ah, Al, Wh2, Wl2, as2, ad2, Hf, asb, adb, N_NODES);
    k_agg8<<<2048, 256, 0, stream>>>(Hf, asb, adb, offs, csrc, b2, Ah, Al, wq + 8);

    // ---- conv3: K=512 (KB=16), Nn=64 (BN=64, NF=2) ----
    k_gemm_mfma<16, 2><<<dim3(MB_TILES, 1), 256, 0, stream>>>(Ah, Al, Wh3, Wl3, Hf3, N_NODES, 64);
    k_alphas1<<<7500, 256, 0, stream>>>(Hf3, as3, ad3, asb, adb);
    k_agg1<<<940, 256, 0, stream>>>(Hf3, asb, adb, offs, csrc, b3, h3);

    // ---- segmented mean-pool + fc ----
    k_poolfc<<<NGRAPH, 128, 0, stream>>>(h3, gstart, Wfc, bfc, out);
}

// Round 12
// 486.487 us; speedup vs baseline: 2.5738x; 2.5738x over previous
//
#include <hip/hip_runtime.h>
#include <hip/hip_fp16.h>
#include <math.h>

#define N_NODES 30000
#define N_EDGES 480000
#define N_EDGES_SL (N_EDGES + N_NODES)
#define DIM_IN 256
#define F1 512   // HEADS*HID
#define HEADS 8
#define NGRAPH 512
#define NEG 0.2f
#define MB_TILES 235  // ceil(30000/128)

typedef __attribute__((ext_vector_type(8))) short short8;
typedef __attribute__((ext_vector_type(4))) float f32x4;

__device__ __forceinline__ float lrelu(float x) { return fmaxf(x, NEG * x); }  // NEG in (0,1)
__device__ __forceinline__ float elu_(float x) { return x > 0.f ? x : __expf(x) - 1.f; }

// split fp32 -> bf16 hi + bf16 lo (round-to-nearest-even both)
__device__ __forceinline__ void cvt_split(float a, unsigned short& h, unsigned short& l) {
    unsigned u = __float_as_uint(a);
    unsigned hb = (u + 0x7fffu + ((u >> 16) & 1u)) >> 16;
    h = (unsigned short)hb;
    float res = a - __uint_as_float(hb << 16);
    unsigned v = __float_as_uint(res);
    l = (unsigned short)((v + 0x7fffu + ((v >> 16) & 1u)) >> 16);
}

// async global->LDS, 16B per lane
__device__ __forceinline__ void glds16(const unsigned short* g, unsigned short* l) {
    __builtin_amdgcn_global_load_lds(
        (const __attribute__((address_space(1))) unsigned int*)g,
        (__attribute__((address_space(3))) unsigned int*)l, 16, 0, 0);
}

// ---------------- CSR build ----------------
__global__ void k_count(const int* __restrict__ ei, int* __restrict__ deg) {
    int i = blockIdx.x * blockDim.x + threadIdx.x;
    if (i < N_EDGES) atomicAdd(&deg[ei[N_EDGES + i]], 1);
}

// single-block 1024-thread scan (16 waves hide load latency)
__global__ __launch_bounds__(1024) void k_scan2(const int* __restrict__ deg,
                                                int* __restrict__ offs,
                                                int* __restrict__ cursor) {
    const int t = threadIdx.x;
    int lo = t * 30;                        // 1024*30 = 30720 >= 30000
    int hi = min(lo + 30, N_NODES);
    int s = 0;
    for (int i = lo; i < hi; ++i) s += deg[i] + 1;  // +1: self-loop
    __shared__ int p[1024];
    p[t] = s;
    __syncthreads();
    for (int off = 1; off < 1024; off <<= 1) {
        int v = (t >= off) ? p[t - off] : 0;
        __syncthreads();
        p[t] += v;
        __syncthreads();
    }
    int run = p[t] - s;  // exclusive
    for (int i = lo; i < hi; ++i) {
        int d = deg[i];  // read BEFORE cursor write (cursor aliases deg)
        offs[i] = run;
        cursor[i] = run;
        run += d + 1;
    }
    if (t == 1023) offs[N_NODES] = p[1023];
}

__global__ void k_scatter(const int* __restrict__ ei, int* __restrict__ cursor,
                          int* __restrict__ csrc) {
    int i = blockIdx.x * blockDim.x + threadIdx.x;
    if (i >= N_EDGES_SL) return;
    int s, d;
    if (i < N_EDGES) { s = ei[i]; d = ei[N_EDGES + i]; }
    else { s = d = i - N_EDGES; }
    int p = atomicAdd(&cursor[d], 1);
    csrc[p] = s;
}

// ---------------- merged pack + bounds (all depend only on inputs) ----------------
__device__ __forceinline__ void d_packA(int t, const float* __restrict__ A,
                                        unsigned short* __restrict__ hi,
                                        unsigned short* __restrict__ lo,
                                        int M, int K) {
    int KB = K >> 5;
    int k8 = t & 3;
    int ml = (t >> 2) & 127;
    int tmp = t >> 9;
    int kb = tmp % KB;
    int mb = tmp / KB;
    int m = mb * 128 + ml;
    int k0 = kb * 32 + k8 * 8;
    float v[8] = {0.f, 0.f, 0.f, 0.f, 0.f, 0.f, 0.f, 0.f};
    if (m < M) {
        float4 p0 = *(const float4*)(A + (size_t)m * K + k0);
        float4 p1 = *(const float4*)(A + (size_t)m * K + k0 + 4);
        v[0] = p0.x; v[1] = p0.y; v[2] = p0.z; v[3] = p0.w;
        v[4] = p1.x; v[5] = p1.y; v[6] = p1.z; v[7] = p1.w;
    }
    unsigned short h[8], l[8];
#pragma unroll
    for (int j = 0; j < 8; ++j) cvt_split(v[j], h[j], l[j]);
    size_t o = (size_t)t * 8;
    *(short8*)(hi + o) = *(short8*)h;
    *(short8*)(lo + o) = *(short8*)l;
}

__device__ __forceinline__ void d_packW(int t, const float* __restrict__ W,
                                        unsigned short* __restrict__ hi,
                                        unsigned short* __restrict__ lo,
                                        int K, int Nn, int BN, int LB) {
    int KB = K >> 5;
    int k8 = t & 3;
    int tmp = t >> 2;
    int nl = tmp & (BN - 1);
    int tmp2 = tmp >> LB;
    int kb = tmp2 % KB;
    int nb = tmp2 / KB;
    int n = nb * BN + nl;
    int k0 = kb * 32 + k8 * 8;
    unsigned short h[8], l[8];
#pragma unroll
    for (int j = 0; j < 8; ++j) cvt_split(W[(size_t)(k0 + j) * Nn + n], h[j], l[j]);
    size_t o = (size_t)t * 8;
    *(short8*)(hi + o) = *(short8*)h;
    *(short8*)(lo + o) = *(short8*)l;
}

#define PB_A 3760
#define PB_W1 64
#define PB_W2 128
#define PB_W3 16
__global__ __launch_bounds__(256) void k_packall(
        const float* __restrict__ x, const float* __restrict__ W1,
        const float* __restrict__ W2, const float* __restrict__ W3,
        const int* __restrict__ batch,
        unsigned short* __restrict__ Ah, unsigned short* __restrict__ Al,
        unsigned short* __restrict__ Wh1, unsigned short* __restrict__ Wl1,
        unsigned short* __restrict__ Wh2, unsigned short* __restrict__ Wl2,
        unsigned short* __restrict__ Wh3, unsigned short* __restrict__ Wl3,
        int* __restrict__ gstart) {
    int b = blockIdx.x, tid = threadIdx.x;
    if (b < PB_A) {
        d_packA(b * 256 + tid, x, Ah, Al, N_NODES, DIM_IN);
    } else if (b < PB_A + PB_W1) {
        d_packW((b - PB_A) * 256 + tid, W1, Wh1, Wl1, DIM_IN, F1, 128, 7);
    } else if (b < PB_A + PB_W1 + PB_W2) {
        d_packW((b - PB_A - PB_W1) * 256 + tid, W2, Wh2, Wl2, F1, F1, 128, 7);
    } else if (b < PB_A + PB_W1 + PB_W2 + PB_W3) {
        d_packW((b - PB_A - PB_W1 - PB_W2) * 256 + tid, W3, Wh3, Wl3, F1, 64, 64, 6);
    } else {
        int bb = b - (PB_A + PB_W1 + PB_W2 + PB_W3);
        int i = bb * 256 + tid;
        if (i >= N_NODES) return;
        int bt = batch[i];
        int pb = (i == 0) ? -1 : batch[i - 1];
        for (int g = pb + 1; g <= bt; ++g) gstart[g] = i;
        if (i == N_NODES - 1)
            for (int g = bt + 1; g <= NGRAPH; ++g) gstart[g] = N_NODES;
    }
}
#define PACKALL_BLOCKS (PB_A + PB_W1 + PB_W2 + PB_W3 + 118)

// ---------------- split-bf16 MFMA GEMM, 8-head conv (Nn=512, BN=128, NF=4) ----------
// Fused epilogue: H fp16 head-split [head][node][64]; alphas head-split [head][node].
template <int KB>
__global__ __launch_bounds__(256) void k_gemm8(const unsigned short* __restrict__ Ah,
                                               const unsigned short* __restrict__ Al,
                                               const unsigned short* __restrict__ Bh,
                                               const unsigned short* __restrict__ Bl,
                                               const float* __restrict__ a_src,
                                               const float* __restrict__ a_dst,
                                               __half* __restrict__ Hf,
                                               float* __restrict__ as_,
                                               float* __restrict__ ad_,
                                               int M) {
    __shared__ unsigned short sAh[4096], sAl[4096], sBh[4096], sBl[4096];
    const int tid = threadIdx.x, lane = tid & 63, wave = tid >> 6;
    const int mb = blockIdx.x, nb = blockIdx.y;
    const int wm = (wave >> 1) * 64;
    const int wn = (wave & 1) * 64;
    const int fr = lane & 15, quad = lane >> 4;

    const unsigned short* pAh = Ah + (size_t)mb * KB * 4096;
    const unsigned short* pAl = Al + (size_t)mb * KB * 4096;
    const unsigned short* pBh = Bh + (size_t)nb * KB * 4096;
    const unsigned short* pBl = Bl + (size_t)nb * KB * 4096;

    f32x4 acc[4][4];
#pragma unroll
    for (int i = 0; i < 4; ++i)
#pragma unroll
        for (int j = 0; j < 4; ++j) acc[i][j] = {0.f, 0.f, 0.f, 0.f};

    for (int kb = 0; kb < KB; ++kb) {
        const unsigned short* ah_g = pAh + kb * 4096;
        const unsigned short* al_g = pAl + kb * 4096;
        const unsigned short* bh_g = pBh + kb * 4096;
        const unsigned short* bl_g = pBl + kb * 4096;
#pragma unroll
        for (int s = 0; s < 2; ++s) {
            int sg = wave * 2 + s;
            glds16(ah_g + sg * 512 + lane * 8, &sAh[sg * 512]);
            glds16(al_g + sg * 512 + lane * 8, &sAl[sg * 512]);
            glds16(bh_g + sg * 512 + lane * 8, &sBh[sg * 512]);
            glds16(bl_g + sg * 512 + lane * 8, &sBl[sg * 512]);
        }
        __syncthreads();

        short8 af_h[4], af_l[4], bf_h[4], bf_l[4];
#pragma unroll
        for (int f = 0; f < 4; ++f) {
            int m = wm + f * 16 + fr;
            af_h[f] = *(const short8*)&sAh[m * 32 + quad * 8];
            af_l[f] = *(const short8*)&sAl[m * 32 + quad * 8];
            int n = wn + f * 16 + fr;
            bf_h[f] = *(const short8*)&sBh[n * 32 + quad * 8];
            bf_l[f] = *(const short8*)&sBl[n * 32 + quad * 8];
        }
#pragma unroll
        for (int i = 0; i < 4; ++i)
#pragma unroll
            for (int j = 0; j < 4; ++j) {
                acc[i][j] = __builtin_amdgcn_mfma_f32_16x16x32_bf16(af_h[i], bf_h[j], acc[i][j], 0, 0, 0);
                acc[i][j] = __builtin_amdgcn_mfma_f32_16x16x32_bf16(af_h[i], bf_l[j], acc[i][j], 0, 0, 0);
                acc[i][j] = __builtin_amdgcn_mfma_f32_16x16x32_bf16(af_l[i], bf_h[j], acc[i][j], 0, 0, 0);
            }
        __syncthreads();
    }
    // epilogue; C/D layout: col=lane&15, row=quad*4+reg
    const int head = (nb * 128 + wn) >> 6;  // wave's 64 cols = one head
    float avs[4], avd[4];
#pragma unroll
    for (int j = 0; j < 4; ++j) {
        avs[j] = a_src[head * 64 + j * 16 + fr];
        avd[j] = a_dst[head * 64 + j * 16 + fr];
    }
    __half* Hh = Hf + (size_t)head * N_NODES * 64;
#pragma unroll
    for (int i = 0; i < 4; ++i) {
#pragma unroll
        for (int r = 0; r < 4; ++r) {
            int row = mb * 128 + wm + i * 16 + quad * 4 + r;
            bool ok = row < M;
            float vs = 0.f, vd = 0.f;
#pragma unroll
            for (int j = 0; j < 4; ++j) {
                float c = acc[i][j][r];
                vs = fmaf(c, avs[j], vs);
                vd = fmaf(c, avd[j], vd);
                if (ok) Hh[(size_t)row * 64 + j * 16 + fr] = __float2half(c);
            }
#pragma unroll
            for (int off = 1; off < 16; off <<= 1) {
                vs += __shfl_xor(vs, off);
                vd += __shfl_xor(vd, off);
            }
            if (ok && fr == 0) {
                as_[head * N_NODES + row] = vs;
                ad_[head * N_NODES + row] = vd;
            }
        }
    }
}

// ---------------- split-bf16 MFMA GEMM, fp16 out (conv3: Nn=64) ----------
template <int KB, int NF>
__global__ __launch_bounds__(256) void k_gemm_mfma(const unsigned short* __restrict__ Ah,
                                                   const unsigned short* __restrict__ Al,
                                                   const unsigned short* __restrict__ Bh,
                                                   const unsigned short* __restrict__ Bl,
                                                   __half* __restrict__ C,
                                                   int M, int Nn) {
    constexpr int BN = NF * 32;
    constexpr int SBW = BN / 64;
    __shared__ unsigned short sAh[4096], sAl[4096], sBh[BN * 32], sBl[BN * 32];
    const int tid = threadIdx.x, lane = tid & 63, wave = tid >> 6;
    const int mb = blockIdx.x, nb = blockIdx.y;
    const int wm = (wave >> 1) * 64;
    const int wn = (wave & 1) * (BN / 2);
    const int fr = lane & 15, quad = lane >> 4;

    const unsigned short* pAh = Ah + (size_t)mb * KB * 4096;
    const unsigned short* pAl = Al + (size_t)mb * KB * 4096;
    const unsigned short* pBh = Bh + (size_t)nb * KB * (BN * 32);
    const unsigned short* pBl = Bl + (size_t)nb * KB * (BN * 32);

    f32x4 acc[4][NF];
#pragma unroll
    for (int i = 0; i < 4; ++i)
#pragma unroll
        for (int j = 0; j < NF; ++j) acc[i][j] = {0.f, 0.f, 0.f, 0.f};

    for (int kb = 0; kb < KB; ++kb) {
        const unsigned short* ah_g = pAh + kb * 4096;
        const unsigned short* al_g = pAl + kb * 4096;
        const unsigned short* bh_g = pBh + kb * (BN * 32);
        const unsigned short* bl_g = pBl + kb * (BN * 32);
#pragma unroll
        for (int s = 0; s < 2; ++s) {
            int sg = wave * 2 + s;
            glds16(ah_g + sg * 512 + lane * 8, &sAh[sg * 512]);
            glds16(al_g + sg * 512 + lane * 8, &sAl[sg * 512]);
        }
#pragma unroll
        for (int s = 0; s < SBW; ++s) {
            int sg = wave * SBW + s;
            glds16(bh_g + sg * 512 + lane * 8, &sBh[sg * 512]);
            glds16(bl_g + sg * 512 + lane * 8, &sBl[sg * 512]);
        }
        __syncthreads();

        short8 af_h[4], af_l[4], bf_h[NF], bf_l[NF];
#pragma unroll
        for (int f = 0; f < 4; ++f) {
            int m = wm + f * 16 + fr;
            af_h[f] = *(const short8*)&sAh[m * 32 + quad * 8];
            af_l[f] = *(const short8*)&sAl[m * 32 + quad * 8];
        }
#pragma unroll
        for (int f = 0; f < NF; ++f) {
            int n = wn + f * 16 + fr;
            bf_h[f] = *(const short8*)&sBh[n * 32 + quad * 8];
            bf_l[f] = *(const short8*)&sBl[n * 32 + quad * 8];
        }
#pragma unroll
        for (int i = 0; i < 4; ++i)
#pragma unroll
            for (int j = 0; j < NF; ++j) {
                acc[i][j] = __builtin_amdgcn_mfma_f32_16x16x32_bf16(af_h[i], bf_h[j], acc[i][j], 0, 0, 0);
                acc[i][j] = __builtin_amdgcn_mfma_f32_16x16x32_bf16(af_h[i], bf_l[j], acc[i][j], 0, 0, 0);
                acc[i][j] = __builtin_amdgcn_mfma_f32_16x16x32_bf16(af_l[i], bf_h[j], acc[i][j], 0, 0, 0);
            }
        __syncthreads();
    }
#pragma unroll
    for (int i = 0; i < 4; ++i) {
#pragma unroll
        for (int r = 0; r < 4; ++r) {
            int row = mb * 128 + wm + i * 16 + quad * 4 + r;
            if (row < M) {
#pragma unroll
                for (int j = 0; j < NF; ++j)
                    C[(size_t)row * Nn + nb * BN + wn + j * 16 + fr] =
                        __float2half(acc[i][j][r]);
            }
        }
    }
}

// process one gathered edge: w*H[src] into 8-channel accumulator (v_fma_mix path)
__device__ __forceinline__ void edge_fma(float w, uint4 u, float* a) {
    const _Float16* hp = (const _Float16*)&u;
#pragma unroll
    for (int k = 0; k < 8; ++k) a[k] = fmaf(w, (float)hp[k], a[k]);
}

// ---------------- softmax-aggregate (8 heads), head-split, XCD-affine --------------
// One wave = 8 dsts x 1 head; lane owns (dst = lane>>3, 8 ch = lane&7). Single pass,
// inline exp, STATIC octet stride (R11's dynamic queue serialized on one cache line:
// 443 us @ 8.5% VALUBusy — never again). Unsigned 32-bit gather offsets.
// head = blockIdx&7 pins head to XCD (2048 co-resident blocks).
__global__ __launch_bounds__(256) void k_agg8(const __half* __restrict__ Hf,
                                              const float* __restrict__ as_,
                                              const float* __restrict__ ad_,
                                              const int* __restrict__ offs,
                                              const int* __restrict__ csrc,
                                              const float* __restrict__ bias,
                                              unsigned short* __restrict__ outh,
                                              unsigned short* __restrict__ outl) {
    const int head = blockIdx.x & 7;
    const int bg = blockIdx.x >> 3;  // 0..255
    const int wave = threadIdx.x >> 6, lane = threadIdx.x & 63;
    const int g = lane >> 3, cl = lane & 7;
    const unsigned coff = (unsigned)(cl * 8);
    const __half* Hh = Hf + (size_t)head * N_NODES * 64;
    const float* ash = as_ + head * N_NODES;
    const float* adh = ad_ + head * N_NODES;
    float bia[8];
#pragma unroll
    for (int j = 0; j < 8; ++j) bia[j] = bias[head * 64 + cl * 8 + j];

    // N_NODES % 8 == 0 -> every octet fully valid
    for (int d0 = (bg * 4 + wave) * 8; d0 < N_NODES; d0 += 8192) {
        int dst = d0 + g;
        int beg = offs[dst], end = offs[dst + 1];
        float adv = adh[dst];
        const int* cp = csrc + beg;
        int deg = end - beg;
        float s = 0.f;
        float a[8] = {0.f, 0.f, 0.f, 0.f, 0.f, 0.f, 0.f, 0.f};
        float b[8] = {0.f, 0.f, 0.f, 0.f, 0.f, 0.f, 0.f, 0.f};
        int loc = 0;
        for (; loc + 3 < deg; loc += 4) {
            unsigned s0 = (unsigned)cp[loc], s1 = (unsigned)cp[loc + 1];
            unsigned s2 = (unsigned)cp[loc + 2], s3 = (unsigned)cp[loc + 3];
            float e0 = ash[s0], e1 = ash[s1], e2 = ash[s2], e3 = ash[s3];
            uint4 u0 = *(const uint4*)(Hh + s0 * 64u + coff);
            uint4 u1 = *(const uint4*)(Hh + s1 * 64u + coff);
            uint4 u2 = *(const uint4*)(Hh + s2 * 64u + coff);
            uint4 u3 = *(const uint4*)(Hh + s3 * 64u + coff);
            float w0 = __expf(lrelu(e0 + adv));
            float w1 = __expf(lrelu(e1 + adv));
            float w2 = __expf(lrelu(e2 + adv));
            float w3 = __expf(lrelu(e3 + adv));
            s += (w0 + w1) + (w2 + w3);
            edge_fma(w0, u0, a);
            edge_fma(w1, u1, b);
            edge_fma(w2, u2, a);
            edge_fma(w3, u3, b);
        }
        for (; loc < deg; ++loc) {
            unsigned s0 = (unsigned)cp[loc];
            float w = __expf(lrelu(ash[s0] + adv));
            uint4 u = *(const uint4*)(Hh + s0 * 64u + coff);
            s += w;
            edge_fma(w, u, a);
        }
        float inv = 1.f / s;
        float o[8];
#pragma unroll
        for (int k = 0; k < 8; ++k) o[k] = elu_((a[k] + b[k]) * inv + bia[k]);
        unsigned short h[8], l[8];
#pragma unroll
        for (int k = 0; k < 8; ++k) cvt_split(o[k], h[k], l[k]);
        // packed A-tile write: global ch c0 = head*64 + cl*8
        int c0 = head * 64 + cl * 8;
        int kb = c0 >> 5, kl = c0 & 31;
        int mb = dst >> 7, ml = dst & 127;
        size_t oo = (((size_t)(mb * 16 + kb) * 128 + ml) * 32 + kl);
        *(short8*)(outh + oo) = *(short8*)h;
        *(short8*)(outl + oo) = *(short8*)l;
    }
}

// ---------------- conv3: 1 head x 64 ch ----------------
__global__ __launch_bounds__(256) void k_alphas1(const __half* __restrict__ H,
                                                 const float* __restrict__ a_src,
                                                 const float* __restrict__ a_dst,
                                                 float* __restrict__ as_,
                                                 float* __restrict__ ad_) {
    int wid = blockIdx.x * 4 + (threadIdx.x >> 6);
    int lane = threadIdx.x & 63;
    if (wid >= N_NODES) return;
    float h = __half2float(H[(size_t)wid * 64 + lane]);
    float ps = h * a_src[lane];
    float pd = h * a_dst[lane];
#pragma unroll
    for (int off = 1; off < 64; off <<= 1) {
        ps += __shfl_xor(ps, off);
        pd += __shfl_xor(pd, off);
    }
    if (lane == 0) { as_[wid] = ps; ad_[wid] = pd; }
}

// single-pass, 4-deep pipeline; writes h3 [node][64] fp32
__global__ __launch_bounds__(256) void k_agg1(const __half* __restrict__ Hf,
                                              const float* __restrict__ as_,
                                              const float* __restrict__ ad_,
                                              const int* __restrict__ offs,
                                              const int* __restrict__ csrc,
                                              const float* __restrict__ bias,
                                              float* __restrict__ h3) {
    const int wave = threadIdx.x >> 6, lane = threadIdx.x & 63;
    const int g = lane >> 3, cl = lane & 7;
    const unsigned coff = (unsigned)(cl * 8);
    int d0 = (blockIdx.x * 4 + wave) * 8;  // grid 940 -> 3760 octets >= 3750
    if (d0 >= N_NODES) return;
    int dst = d0 + g;
    float bia[8];
#pragma unroll
    for (int j = 0; j < 8; ++j) bia[j] = bias[cl * 8 + j];
    int beg = offs[dst], end = offs[dst + 1];
    float adv = ad_[dst];
    const int* cp = csrc + beg;
    int deg = end - beg;
    float s = 0.f;
    float a[8] = {0.f, 0.f, 0.f, 0.f, 0.f, 0.f, 0.f, 0.f};
    float b[8] = {0.f, 0.f, 0.f, 0.f, 0.f, 0.f, 0.f, 0.f};
    int loc = 0;
    for (; loc + 3 < deg; loc += 4) {
        unsigned s0 = (unsigned)cp[loc], s1 = (unsigned)cp[loc + 1];
        unsigned s2 = (unsigned)cp[loc + 2], s3 = (unsigned)cp[loc + 3];
        float e0 = as_[s0], e1 = as_[s1], e2 = as_[s2], e3 = as_[s3];
        uint4 u0 = *(const uint4*)(Hf + s0 * 64u + coff);
        uint4 u1 = *(const uint4*)(Hf + s1 * 64u + coff);
        uint4 u2 = *(const uint4*)(Hf + s2 * 64u + coff);
        uint4 u3 = *(const uint4*)(Hf + s3 * 64u + coff);
        float w0 = __expf(lrelu(e0 + adv));
        float w1 = __expf(lrelu(e1 + adv));
        float w2 = __expf(lrelu(e2 + adv));
        float w3 = __expf(lrelu(e3 + adv));
        s += (w0 + w1) + (w2 + w3);
        edge_fma(w0, u0, a);
        edge_fma(w1, u1, b);
        edge_fma(w2, u2, a);
        edge_fma(w3, u3, b);
    }
    for (; loc < deg; ++loc) {
        unsigned s0 = (unsigned)cp[loc];
        float w = __expf(lrelu(as_[s0] + adv));
        uint4 u = *(const uint4*)(Hf + s0 * 64u + coff);
        s += w;
        edge_fma(w, u, a);
    }
    float inv = 1.f / s;
    float o[8];
#pragma unroll
    for (int k = 0; k < 8; ++k) o[k] = elu_((a[k] + b[k]) * inv + bia[k]);
    float* op = h3 + (size_t)dst * 64 + cl * 8;
    *(float4*)op = make_float4(o[0], o[1], o[2], o[3]);
    *(float4*)(op + 4) = make_float4(o[4], o[5], o[6], o[7]);
}

// ---------------- segmented mean-pool (sorted batch) + fc, no atomics ----------
__global__ __launch_bounds__(128) void k_poolfc(const float* __restrict__ h3,
                                                const int* __restrict__ gstart,
                                                const float* __restrict__ W,
                                                const float* __restrict__ b,
                                                float* __restrict__ out) {
    int g = blockIdx.x;
    int t = threadIdx.x;  // 128
    int s0 = gstart[g], s1 = gstart[g + 1];
    int c = t & 63, half = t >> 6;
    float acc = 0.f;
    for (int r = s0 + half; r < s1; r += 2) acc += h3[(size_t)r * 64 + c];
    __shared__ float p2[128];
    __shared__ float p[64];
    p2[t] = acc;
    __syncthreads();
    if (t < 64) {
        float cntf = (float)(s1 - s0);
        p[t] = (p2[t] + p2[t + 64]) / fmaxf(cntf, 1.f);
    }
    __syncthreads();
    float o = b[t];
#pragma unroll
    for (int k = 0; k < 64; ++k) o = fmaf(p[k], W[k * 128 + t], o);
    out[g * 128 + t] = o;
}

extern "C" void kernel_launch(void* const* d_in, const int* in_sizes, int n_in,
                              void* d_out, int out_size, void* d_ws, size_t ws_size,
                              hipStream_t stream) {
    const float* x     = (const float*)d_in[0];
    const int*   ei    = (const int*)d_in[1];
    const int*   batch = (const int*)d_in[2];
    const float* W1    = (const float*)d_in[3];
    const float* as1   = (const float*)d_in[4];
    const float* ad1   = (const float*)d_in[5];
    const float* b1    = (const float*)d_in[6];
    const float* W2    = (const float*)d_in[7];
    const float* as2   = (const float*)d_in[8];
    const float* ad2   = (const float*)d_in[9];
    const float* b2    = (const float*)d_in[10];
    const float* W3    = (const float*)d_in[11];
    const float* as3   = (const float*)d_in[12];
    const float* ad3   = (const float*)d_in[13];
    const float* b3    = (const float*)d_in[14];
    const float* Wfc   = (const float*)d_in[15];
    const float* bfc   = (const float*)d_in[16];
    float* out = (float*)d_out;

    char* ws = (char*)d_ws;
    size_t off = 0;
    auto alloc = [&](size_t bytes) -> void* {
        void* p = ws + off;
        off += (bytes + 255) & ~(size_t)255;
        return p;
    };
    __half* Hf = (__half*)alloc((size_t)HEADS * N_NODES * 64 * 2);  // [head][node][64]
    __half* Hf3 = (__half*)alloc((size_t)N_NODES * 64 * 2);
    float* h3 = (float*)alloc((size_t)N_NODES * 64 * 4);
    unsigned short* Ah = (unsigned short*)alloc((size_t)MB_TILES * 16 * 4096 * 2);
    unsigned short* Al = (unsigned short*)alloc((size_t)MB_TILES * 16 * 4096 * 2);
    unsigned short* Wh1 = (unsigned short*)alloc((size_t)131072 * 2);
    unsigned short* Wl1 = (unsigned short*)alloc((size_t)131072 * 2);
    unsigned short* Wh2 = (unsigned short*)alloc((size_t)262144 * 2);
    unsigned short* Wl2 = (unsigned short*)alloc((size_t)262144 * 2);
    unsigned short* Wh3 = (unsigned short*)alloc((size_t)32768 * 2);
    unsigned short* Wl3 = (unsigned short*)alloc((size_t)32768 * 2);
    float* asb   = (float*)alloc((size_t)HEADS * N_NODES * 4);  // [head][node]
    float* adb   = (float*)alloc((size_t)HEADS * N_NODES * 4);
    int*   offs  = (int*)alloc((N_NODES + 1) * 4);
    int*   deg   = (int*)alloc(N_NODES * 4);   // reused as scatter cursor
    int*   csrc  = (int*)alloc((size_t)N_EDGES_SL * 4);
    int*   gstart= (int*)alloc((NGRAPH + 1) * 4);

    hipMemsetAsync(deg, 0, N_NODES * 4, stream);

    // pack everything + graph bounds (depends only on inputs)
    k_packall<<<PACKALL_BLOCKS, 256, 0, stream>>>(x, W1, W2, W3, batch, Ah, Al,
                                                  Wh1, Wl1, Wh2, Wl2, Wh3, Wl3, gstart);
    // CSR build
    k_count<<<(N_EDGES + 255) / 256, 256, 0, stream>>>(ei, deg);
    k_scan2<<<1, 1024, 0, stream>>>(deg, offs, deg);
    k_scatter<<<(N_EDGES_SL + 255) / 256, 256, 0, stream>>>(ei, deg, csrc);

    // ---- conv1: K=256 (KB=8) ----
    k_gemm8<8><<<dim3(MB_TILES, 4), 256, 0, stream>>>(Ah, Al, Wh1, Wl1, as1, ad1, Hf, asb, adb, N_NODES);
    k_agg8<<<2048, 256, 0, stream>>>(Hf, asb, adb, offs, csrc, b1, Ah, Al);

    // ---- conv2: K=512 (KB=16) ----
    k_gemm8<16><<<dim3(MB_TILES, 4), 256, 0, stream>>>(Ah, Al, Wh2, Wl2, as2, ad2, Hf, asb, adb, N_NODES);
    k_agg8<<<2048, 256, 0, stream>>>(Hf, asb, adb, offs, csrc, b2, Ah, Al);

    // ---- conv3: K=512 (KB=16), Nn=64 (BN=64, NF=2) ----
    k_gemm_mfma<16, 2><<<dim3(MB_TILES, 1), 256, 0, stream>>>(Ah, Al, Wh3, Wl3, Hf3, N_NODES, 64);
    k_alphas1<<<7500, 256, 0, stream>>>(Hf3, as3, ad3, asb, adb);
    k_agg1<<<940, 256, 0, stream>>>(Hf3, asb, adb, offs, csrc, b3, h3);

    // ---- segmented mean-pool + fc ----
    k_poolfc<<<NGRAPH, 128, 0, stream>>>(h3, gstart, Wfc, bfc, out);
}

// Round 13
// 436.281 us; speedup vs baseline: 2.8700x; 1.1151x over previous
//
#include <hip/hip_runtime.h>
#include <hip/hip_fp16.h>
#include <math.h>

#define N_NODES 30000
#define N_EDGES 480000
#define N_EDGES_SL (N_EDGES + N_NODES)
#define DIM_IN 256
#define F1 512   // HEADS*HID
#define HEADS 8
#define NGRAPH 512
#define NEG 0.2f
#define MB_TILES 235  // ceil(30000/128)
#define NB_SCAN 118   // ceil(30000/256)

typedef __attribute__((ext_vector_type(8))) short short8;
typedef __attribute__((ext_vector_type(4))) float f32x4;

__device__ __forceinline__ float lrelu(float x) { return fmaxf(x, NEG * x); }  // NEG in (0,1)
__device__ __forceinline__ float elu_(float x) { return x > 0.f ? x : __expf(x) - 1.f; }

// split fp32 -> bf16 hi + bf16 lo (round-to-nearest-even both)
__device__ __forceinline__ void cvt_split(float a, unsigned short& h, unsigned short& l) {
    unsigned u = __float_as_uint(a);
    unsigned hb = (u + 0x7fffu + ((u >> 16) & 1u)) >> 16;
    h = (unsigned short)hb;
    float res = a - __uint_as_float(hb << 16);
    unsigned v = __float_as_uint(res);
    l = (unsigned short)((v + 0x7fffu + ((v >> 16) & 1u)) >> 16);
}

// async global->LDS, 16B per lane
__device__ __forceinline__ void glds16(const unsigned short* g, unsigned short* l) {
    __builtin_amdgcn_global_load_lds(
        (const __attribute__((address_space(1))) unsigned int*)g,
        (__attribute__((address_space(3))) unsigned int*)l, 16, 0, 0);
}

// ---------------- CSR build ----------------
__global__ void k_count(const int* __restrict__ ei, int* __restrict__ deg) {
    int i = blockIdx.x * blockDim.x + threadIdx.x;
    if (i < N_EDGES) atomicAdd(&deg[ei[N_EDGES + i]], 1);
}

// 3-phase parallel scan (R10-measured; R12's 1024-thread k_scan2 regressed ~35us)
__global__ __launch_bounds__(256) void k_bsum(const int* __restrict__ deg,
                                              int* __restrict__ bsum) {
    int i = blockIdx.x * 256 + threadIdx.x;
    int v = (i < N_NODES) ? deg[i] + 1 : 0;  // +1: self-loop
#pragma unroll
    for (int off = 1; off < 64; off <<= 1) v += __shfl_xor(v, off);
    __shared__ int ws[4];
    if ((threadIdx.x & 63) == 0) ws[threadIdx.x >> 6] = v;
    __syncthreads();
    if (threadIdx.x == 0) bsum[blockIdx.x] = ws[0] + ws[1] + ws[2] + ws[3];
}

__global__ __launch_bounds__(128) void k_bscan(const int* __restrict__ bsum,
                                               int* __restrict__ bbase,
                                               int* __restrict__ offsN) {
    __shared__ int p[128];
    int t = threadIdx.x;
    int v = (t < NB_SCAN) ? bsum[t] : 0;
    p[t] = v;
    __syncthreads();
    for (int off = 1; off < 128; off <<= 1) {
        int x = (t >= off) ? p[t - off] : 0;
        __syncthreads();
        p[t] += x;
        __syncthreads();
    }
    if (t < NB_SCAN) bbase[t] = p[t] - v;  // exclusive
    if (t == 127) *offsN = p[127];         // grand total -> offs[N_NODES]
}

__global__ __launch_bounds__(256) void k_offs(const int* __restrict__ deg,
                                              const int* __restrict__ bbase,
                                              int* __restrict__ offs,
                                              int* __restrict__ cursor) {
    int b = blockIdx.x, t = threadIdx.x;
    int i = b * 256 + t;
    int v = (i < N_NODES) ? deg[i] + 1 : 0;  // read BEFORE cursor write (aliases deg)
    __shared__ int p[256];
    p[t] = v;
    __syncthreads();
    for (int off = 1; off < 256; off <<= 1) {
        int x = (t >= off) ? p[t - off] : 0;
        __syncthreads();
        p[t] += x;
        __syncthreads();
    }
    if (i < N_NODES) {
        int excl = bbase[b] + p[t] - v;
        offs[i] = excl;
        cursor[i] = excl;
    }
}

__global__ void k_scatter(const int* __restrict__ ei, int* __restrict__ cursor,
                          int* __restrict__ csrc) {
    int i = blockIdx.x * blockDim.x + threadIdx.x;
    if (i >= N_EDGES_SL) return;
    int s, d;
    if (i < N_EDGES) { s = ei[i]; d = ei[N_EDGES + i]; }
    else { s = d = i - N_EDGES; }
    int p = atomicAdd(&cursor[d], 1);
    csrc[p] = s;
}

// ---------------- merged pack + bounds (all depend only on inputs) ----------------
__device__ __forceinline__ void d_packA(int t, const float* __restrict__ A,
                                        unsigned short* __restrict__ hi,
                                        unsigned short* __restrict__ lo,
                                        int M, int K) {
    int KB = K >> 5;
    int k8 = t & 3;
    int ml = (t >> 2) & 127;
    int tmp = t >> 9;
    int kb = tmp % KB;
    int mb = tmp / KB;
    int m = mb * 128 + ml;
    int k0 = kb * 32 + k8 * 8;
    float v[8] = {0.f, 0.f, 0.f, 0.f, 0.f, 0.f, 0.f, 0.f};
    if (m < M) {
        float4 p0 = *(const float4*)(A + (size_t)m * K + k0);
        float4 p1 = *(const float4*)(A + (size_t)m * K + k0 + 4);
        v[0] = p0.x; v[1] = p0.y; v[2] = p0.z; v[3] = p0.w;
        v[4] = p1.x; v[5] = p1.y; v[6] = p1.z; v[7] = p1.w;
    }
    unsigned short h[8], l[8];
#pragma unroll
    for (int j = 0; j < 8; ++j) cvt_split(v[j], h[j], l[j]);
    size_t o = (size_t)t * 8;
    *(short8*)(hi + o) = *(short8*)h;
    *(short8*)(lo + o) = *(short8*)l;
}

__device__ __forceinline__ void d_packW(int t, const float* __restrict__ W,
                                        unsigned short* __restrict__ hi,
                                        unsigned short* __restrict__ lo,
                                        int K, int Nn, int BN, int LB) {
    int KB = K >> 5;
    int k8 = t & 3;
    int tmp = t >> 2;
    int nl = tmp & (BN - 1);
    int tmp2 = tmp >> LB;
    int kb = tmp2 % KB;
    int nb = tmp2 / KB;
    int n = nb * BN + nl;
    int k0 = kb * 32 + k8 * 8;
    unsigned short h[8], l[8];
#pragma unroll
    for (int j = 0; j < 8; ++j) cvt_split(W[(size_t)(k0 + j) * Nn + n], h[j], l[j]);
    size_t o = (size_t)t * 8;
    *(short8*)(hi + o) = *(short8*)h;
    *(short8*)(lo + o) = *(short8*)l;
}

#define PB_A 3760
#define PB_W1 64
#define PB_W2 128
#define PB_W3 16
__global__ __launch_bounds__(256) void k_packall(
        const float* __restrict__ x, const float* __restrict__ W1,
        const float* __restrict__ W2, const float* __restrict__ W3,
        const int* __restrict__ batch,
        unsigned short* __restrict__ Ah, unsigned short* __restrict__ Al,
        unsigned short* __restrict__ Wh1, unsigned short* __restrict__ Wl1,
        unsigned short* __restrict__ Wh2, unsigned short* __restrict__ Wl2,
        unsigned short* __restrict__ Wh3, unsigned short* __restrict__ Wl3,
        int* __restrict__ gstart) {
    int b = blockIdx.x, tid = threadIdx.x;
    if (b < PB_A) {
        d_packA(b * 256 + tid, x, Ah, Al, N_NODES, DIM_IN);
    } else if (b < PB_A + PB_W1) {
        d_packW((b - PB_A) * 256 + tid, W1, Wh1, Wl1, DIM_IN, F1, 128, 7);
    } else if (b < PB_A + PB_W1 + PB_W2) {
        d_packW((b - PB_A - PB_W1) * 256 + tid, W2, Wh2, Wl2, F1, F1, 128, 7);
    } else if (b < PB_A + PB_W1 + PB_W2 + PB_W3) {
        d_packW((b - PB_A - PB_W1 - PB_W2) * 256 + tid, W3, Wh3, Wl3, F1, 64, 64, 6);
    } else {
        int bb = b - (PB_A + PB_W1 + PB_W2 + PB_W3);
        int i = bb * 256 + tid;
        if (i >= N_NODES) return;
        int bt = batch[i];
        int pb = (i == 0) ? -1 : batch[i - 1];
        for (int g = pb + 1; g <= bt; ++g) gstart[g] = i;
        if (i == N_NODES - 1)
            for (int g = bt + 1; g <= NGRAPH; ++g) gstart[g] = N_NODES;
    }
}
#define PACKALL_BLOCKS (PB_A + PB_W1 + PB_W2 + PB_W3 + 118)

// ---------------- split-bf16 MFMA GEMM, 8-head conv (Nn=512, BN=128, NF=4) ----------
// Fused epilogue: H fp16 head-split [head][node][64]; alphas head-split [head][node].
template <int KB>
__global__ __launch_bounds__(256) void k_gemm8(const unsigned short* __restrict__ Ah,
                                               const unsigned short* __restrict__ Al,
                                               const unsigned short* __restrict__ Bh,
                                               const unsigned short* __restrict__ Bl,
                                               const float* __restrict__ a_src,
                                               const float* __restrict__ a_dst,
                                               __half* __restrict__ Hf,
                                               float* __restrict__ as_,
                                               float* __restrict__ ad_,
                                               int M) {
    __shared__ unsigned short sAh[4096], sAl[4096], sBh[4096], sBl[4096];
    const int tid = threadIdx.x, lane = tid & 63, wave = tid >> 6;
    const int mb = blockIdx.x, nb = blockIdx.y;
    const int wm = (wave >> 1) * 64;
    const int wn = (wave & 1) * 64;
    const int fr = lane & 15, quad = lane >> 4;

    const unsigned short* pAh = Ah + (size_t)mb * KB * 4096;
    const unsigned short* pAl = Al + (size_t)mb * KB * 4096;
    const unsigned short* pBh = Bh + (size_t)nb * KB * 4096;
    const unsigned short* pBl = Bl + (size_t)nb * KB * 4096;

    f32x4 acc[4][4];
#pragma unroll
    for (int i = 0; i < 4; ++i)
#pragma unroll
        for (int j = 0; j < 4; ++j) acc[i][j] = {0.f, 0.f, 0.f, 0.f};

    for (int kb = 0; kb < KB; ++kb) {
        const unsigned short* ah_g = pAh + kb * 4096;
        const unsigned short* al_g = pAl + kb * 4096;
        const unsigned short* bh_g = pBh + kb * 4096;
        const unsigned short* bl_g = pBl + kb * 4096;
#pragma unroll
        for (int s = 0; s < 2; ++s) {
            int sg = wave * 2 + s;
            glds16(ah_g + sg * 512 + lane * 8, &sAh[sg * 512]);
            glds16(al_g + sg * 512 + lane * 8, &sAl[sg * 512]);
            glds16(bh_g + sg * 512 + lane * 8, &sBh[sg * 512]);
            glds16(bl_g + sg * 512 + lane * 8, &sBl[sg * 512]);
        }
        __syncthreads();

        short8 af_h[4], af_l[4], bf_h[4], bf_l[4];
#pragma unroll
        for (int f = 0; f < 4; ++f) {
            int m = wm + f * 16 + fr;
            af_h[f] = *(const short8*)&sAh[m * 32 + quad * 8];
            af_l[f] = *(const short8*)&sAl[m * 32 + quad * 8];
            int n = wn + f * 16 + fr;
            bf_h[f] = *(const short8*)&sBh[n * 32 + quad * 8];
            bf_l[f] = *(const short8*)&sBl[n * 32 + quad * 8];
        }
#pragma unroll
        for (int i = 0; i < 4; ++i)
#pragma unroll
            for (int j = 0; j < 4; ++j) {
                acc[i][j] = __builtin_amdgcn_mfma_f32_16x16x32_bf16(af_h[i], bf_h[j], acc[i][j], 0, 0, 0);
                acc[i][j] = __builtin_amdgcn_mfma_f32_16x16x32_bf16(af_h[i], bf_l[j], acc[i][j], 0, 0, 0);
                acc[i][j] = __builtin_amdgcn_mfma_f32_16x16x32_bf16(af_l[i], bf_h[j], acc[i][j], 0, 0, 0);
            }
        __syncthreads();
    }
    // epilogue; C/D layout: col=lane&15, row=quad*4+reg
    const int head = (nb * 128 + wn) >> 6;  // wave's 64 cols = one head
    float avs[4], avd[4];
#pragma unroll
    for (int j = 0; j < 4; ++j) {
        avs[j] = a_src[head * 64 + j * 16 + fr];
        avd[j] = a_dst[head * 64 + j * 16 + fr];
    }
    __half* Hh = Hf + (size_t)head * N_NODES * 64;
#pragma unroll
    for (int i = 0; i < 4; ++i) {
#pragma unroll
        for (int r = 0; r < 4; ++r) {
            int row = mb * 128 + wm + i * 16 + quad * 4 + r;
            bool ok = row < M;
            float vs = 0.f, vd = 0.f;
#pragma unroll
            for (int j = 0; j < 4; ++j) {
                float c = acc[i][j][r];
                vs = fmaf(c, avs[j], vs);
                vd = fmaf(c, avd[j], vd);
                if (ok) Hh[(size_t)row * 64 + j * 16 + fr] = __float2half(c);
            }
#pragma unroll
            for (int off = 1; off < 16; off <<= 1) {
                vs += __shfl_xor(vs, off);
                vd += __shfl_xor(vd, off);
            }
            if (ok && fr == 0) {
                as_[head * N_NODES + row] = vs;
                ad_[head * N_NODES + row] = vd;
            }
        }
    }
}

// ---------------- conv3 GEMM (Nn=64), fp16 out + FUSED alpha projections ----------
// Each wave covers 32 of the 64 cols; per-row partials reduced over fr via shfl,
// wave pairs combined through reused LDS. Replaces separate k_alphas1.
template <int KB>
__global__ __launch_bounds__(256) void k_gemm1(const unsigned short* __restrict__ Ah,
                                               const unsigned short* __restrict__ Al,
                                               const unsigned short* __restrict__ Bh,
                                               const unsigned short* __restrict__ Bl,
                                               const float* __restrict__ a_src,
                                               const float* __restrict__ a_dst,
                                               __half* __restrict__ C,
                                               float* __restrict__ as_,
                                               float* __restrict__ ad_,
                                               int M) {
    __shared__ unsigned short sAh[4096], sAl[4096], sBh[2048], sBl[2048];
    const int tid = threadIdx.x, lane = tid & 63, wave = tid >> 6;
    const int mb = blockIdx.x;
    const int wm = (wave >> 1) * 64;
    const int wn = (wave & 1) * 32;
    const int fr = lane & 15, quad = lane >> 4;

    const unsigned short* pAh = Ah + (size_t)mb * KB * 4096;
    const unsigned short* pAl = Al + (size_t)mb * KB * 4096;

    f32x4 acc[4][2];
#pragma unroll
    for (int i = 0; i < 4; ++i)
#pragma unroll
        for (int j = 0; j < 2; ++j) acc[i][j] = {0.f, 0.f, 0.f, 0.f};

    for (int kb = 0; kb < KB; ++kb) {
        const unsigned short* ah_g = pAh + kb * 4096;
        const unsigned short* al_g = pAl + kb * 4096;
        const unsigned short* bh_g = Bh + kb * 2048;
        const unsigned short* bl_g = Bl + kb * 2048;
#pragma unroll
        for (int s = 0; s < 2; ++s) {
            int sg = wave * 2 + s;
            glds16(ah_g + sg * 512 + lane * 8, &sAh[sg * 512]);
            glds16(al_g + sg * 512 + lane * 8, &sAl[sg * 512]);
        }
        glds16(bh_g + wave * 512 + lane * 8, &sBh[wave * 512]);
        glds16(bl_g + wave * 512 + lane * 8, &sBl[wave * 512]);
        __syncthreads();

        short8 af_h[4], af_l[4], bf_h[2], bf_l[2];
#pragma unroll
        for (int f = 0; f < 4; ++f) {
            int m = wm + f * 16 + fr;
            af_h[f] = *(const short8*)&sAh[m * 32 + quad * 8];
            af_l[f] = *(const short8*)&sAl[m * 32 + quad * 8];
        }
#pragma unroll
        for (int f = 0; f < 2; ++f) {
            int n = wn + f * 16 + fr;
            bf_h[f] = *(const short8*)&sBh[n * 32 + quad * 8];
            bf_l[f] = *(const short8*)&sBl[n * 32 + quad * 8];
        }
#pragma unroll
        for (int i = 0; i < 4; ++i)
#pragma unroll
            for (int j = 0; j < 2; ++j) {
                acc[i][j] = __builtin_amdgcn_mfma_f32_16x16x32_bf16(af_h[i], bf_h[j], acc[i][j], 0, 0, 0);
                acc[i][j] = __builtin_amdgcn_mfma_f32_16x16x32_bf16(af_h[i], bf_l[j], acc[i][j], 0, 0, 0);
                acc[i][j] = __builtin_amdgcn_mfma_f32_16x16x32_bf16(af_l[i], bf_h[j], acc[i][j], 0, 0, 0);
            }
        __syncthreads();
    }
    // epilogue: Hf3 write + fused alpha projections (a_src/a_dst are 64-wide)
    float avs[2], avd[2];
#pragma unroll
    for (int j = 0; j < 2; ++j) {
        avs[j] = a_src[wn + j * 16 + fr];
        avd[j] = a_dst[wn + j * 16 + fr];
    }
    float* ps = (float*)sAh;  // 256 floats (reused post-loop, all waves past sync)
    float* pd = (float*)sAl;
#pragma unroll
    for (int i = 0; i < 4; ++i) {
#pragma unroll
        for (int r = 0; r < 4; ++r) {
            int rl = wm + i * 16 + quad * 4 + r;  // 0..127 row in block
            int row = mb * 128 + rl;
            bool ok = row < M;
            float vs = 0.f, vd = 0.f;
#pragma unroll
            for (int j = 0; j < 2; ++j) {
                float c = acc[i][j][r];
                vs = fmaf(c, avs[j], vs);
                vd = fmaf(c, avd[j], vd);
                if (ok) C[(size_t)row * 64 + wn + j * 16 + fr] = __float2half(c);
            }
#pragma unroll
            for (int off = 1; off < 16; off <<= 1) {
                vs += __shfl_xor(vs, off);
                vd += __shfl_xor(vd, off);
            }
            if (fr == 0) {
                ps[wave * 64 + (rl & 63)] = vs;
                pd[wave * 64 + (rl & 63)] = vd;
            }
        }
    }
    __syncthreads();
    if (tid < 128) {
        int row = mb * 128 + tid;
        if (row < M) {
            int wp = (tid >> 6) * 2;  // rows 0-63: waves 0+1; rows 64-127: waves 2+3
            as_[row] = ps[wp * 64 + (tid & 63)] + ps[(wp + 1) * 64 + (tid & 63)];
            ad_[row] = pd[wp * 64 + (tid & 63)] + pd[(wp + 1) * 64 + (tid & 63)];
        }
    }
}

// process one gathered edge: w*H[src] into 8-channel accumulator (v_fma_mix path)
__device__ __forceinline__ void edge_fma(float w, uint4 u, float* a) {
    const _Float16* hp = (const _Float16*)&u;
#pragma unroll
    for (int k = 0; k < 8; ++k) a[k] = fmaf(w, (float)hp[k], a[k]);
}

// ---------------- softmax-aggregate (8 heads), head-split, XCD-affine --------------
// One wave = 8 dsts x 1 head; lane owns (dst = lane>>3, 8 ch = lane&7). Single pass,
// inline exp, STATIC octet stride (R11's dynamic queue serialized: never again).
// Unsigned 32-bit gather offsets. head = blockIdx&7 pins head to XCD (2048 blocks).
__global__ __launch_bounds__(256) void k_agg8(const __half* __restrict__ Hf,
                                              const float* __restrict__ as_,
                                              const float* __restrict__ ad_,
                                              const int* __restrict__ offs,
                                              const int* __restrict__ csrc,
                                              const float* __restrict__ bias,
                                              unsigned short* __restrict__ outh,
                                              unsigned short* __restrict__ outl) {
    const int head = blockIdx.x & 7;
    const int bg = blockIdx.x >> 3;  // 0..255
    const int wave = threadIdx.x >> 6, lane = threadIdx.x & 63;
    const int g = lane >> 3, cl = lane & 7;
    const unsigned coff = (unsigned)(cl * 8);
    const __half* Hh = Hf + (size_t)head * N_NODES * 64;
    const float* ash = as_ + head * N_NODES;
    const float* adh = ad_ + head * N_NODES;
    float bia[8];
#pragma unroll
    for (int j = 0; j < 8; ++j) bia[j] = bias[head * 64 + cl * 8 + j];

    // N_NODES % 8 == 0 -> every octet fully valid
    for (int d0 = (bg * 4 + wave) * 8; d0 < N_NODES; d0 += 8192) {
        int dst = d0 + g;
        int beg = offs[dst], end = offs[dst + 1];
        float adv = adh[dst];
        const int* cp = csrc + beg;
        int deg = end - beg;
        float s = 0.f;
        float a[8] = {0.f, 0.f, 0.f, 0.f, 0.f, 0.f, 0.f, 0.f};
        float b[8] = {0.f, 0.f, 0.f, 0.f, 0.f, 0.f, 0.f, 0.f};
        int loc = 0;
        for (; loc + 3 < deg; loc += 4) {
            unsigned s0 = (unsigned)cp[loc], s1 = (unsigned)cp[loc + 1];
            unsigned s2 = (unsigned)cp[loc + 2], s3 = (unsigned)cp[loc + 3];
            float e0 = ash[s0], e1 = ash[s1], e2 = ash[s2], e3 = ash[s3];
            uint4 u0 = *(const uint4*)(Hh + s0 * 64u + coff);
            uint4 u1 = *(const uint4*)(Hh + s1 * 64u + coff);
            uint4 u2 = *(const uint4*)(Hh + s2 * 64u + coff);
            uint4 u3 = *(const uint4*)(Hh + s3 * 64u + coff);
            float w0 = __expf(lrelu(e0 + adv));
            float w1 = __expf(lrelu(e1 + adv));
            float w2 = __expf(lrelu(e2 + adv));
            float w3 = __expf(lrelu(e3 + adv));
            s += (w0 + w1) + (w2 + w3);
            edge_fma(w0, u0, a);
            edge_fma(w1, u1, b);
            edge_fma(w2, u2, a);
            edge_fma(w3, u3, b);
        }
        for (; loc < deg; ++loc) {
            unsigned s0 = (unsigned)cp[loc];
            float w = __expf(lrelu(ash[s0] + adv));
            uint4 u = *(const uint4*)(Hh + s0 * 64u + coff);
            s += w;
            edge_fma(w, u, a);
        }
        float inv = 1.f / s;
        float o[8];
#pragma unroll
        for (int k = 0; k < 8; ++k) o[k] = elu_((a[k] + b[k]) * inv + bia[k]);
        unsigned short h[8], l[8];
#pragma unroll
        for (int k = 0; k < 8; ++k) cvt_split(o[k], h[k], l[k]);
        // packed A-tile write: global ch c0 = head*64 + cl*8
        int c0 = head * 64 + cl * 8;
        int kb = c0 >> 5, kl = c0 & 31;
        int mb = dst >> 7, ml = dst & 127;
        size_t oo = (((size_t)(mb * 16 + kb) * 128 + ml) * 32 + kl);
        *(short8*)(outh + oo) = *(short8*)h;
        *(short8*)(outl + oo) = *(short8*)l;
    }
}

// single-pass, 4-deep pipeline; writes h3 [node][64] fp32
__global__ __launch_bounds__(256) void k_agg1(const __half* __restrict__ Hf,
                                              const float* __restrict__ as_,
                                              const float* __restrict__ ad_,
                                              const int* __restrict__ offs,
                                              const int* __restrict__ csrc,
                                              const float* __restrict__ bias,
                                              float* __restrict__ h3) {
    const int wave = threadIdx.x >> 6, lane = threadIdx.x & 63;
    const int g = lane >> 3, cl = lane & 7;
    const unsigned coff = (unsigned)(cl * 8);
    int d0 = (blockIdx.x * 4 + wave) * 8;  // grid 940 -> 3760 octets >= 3750
    if (d0 >= N_NODES) return;
    int dst = d0 + g;
    float bia[8];
#pragma unroll
    for (int j = 0; j < 8; ++j) bia[j] = bias[cl * 8 + j];
    int beg = offs[dst], end = offs[dst + 1];
    float adv = ad_[dst];
    const int* cp = csrc + beg;
    int deg = end - beg;
    float s = 0.f;
    float a[8] = {0.f, 0.f, 0.f, 0.f, 0.f, 0.f, 0.f, 0.f};
    float b[8] = {0.f, 0.f, 0.f, 0.f, 0.f, 0.f, 0.f, 0.f};
    int loc = 0;
    for (; loc + 3 < deg; loc += 4) {
        unsigned s0 = (unsigned)cp[loc], s1 = (unsigned)cp[loc + 1];
        unsigned s2 = (unsigned)cp[loc + 2], s3 = (unsigned)cp[loc + 3];
        float e0 = as_[s0], e1 = as_[s1], e2 = as_[s2], e3 = as_[s3];
        uint4 u0 = *(const uint4*)(Hf + s0 * 64u + coff);
        uint4 u1 = *(const uint4*)(Hf + s1 * 64u + coff);
        uint4 u2 = *(const uint4*)(Hf + s2 * 64u + coff);
        uint4 u3 = *(const uint4*)(Hf + s3 * 64u + coff);
        float w0 = __expf(lrelu(e0 + adv));
        float w1 = __expf(lrelu(e1 + adv));
        float w2 = __expf(lrelu(e2 + adv));
        float w3 = __expf(lrelu(e3 + adv));
        s += (w0 + w1) + (w2 + w3);
        edge_fma(w0, u0, a);
        edge_fma(w1, u1, b);
        edge_fma(w2, u2, a);
        edge_fma(w3, u3, b);
    }
    for (; loc < deg; ++loc) {
        unsigned s0 = (unsigned)cp[loc];
        float w = __expf(lrelu(as_[s0] + adv));
        uint4 u = *(const uint4*)(Hf + s0 * 64u + coff);
        s += w;
        edge_fma(w, u, a);
    }
    float inv = 1.f / s;
    float o[8];
#pragma unroll
    for (int k = 0; k < 8; ++k) o[k] = elu_((a[k] + b[k]) * inv + bia[k]);
    float* op = h3 + (size_t)dst * 64 + cl * 8;
    *(float4*)op = make_float4(o[0], o[1], o[2], o[3]);
    *(float4*)(op + 4) = make_float4(o[4], o[5], o[6], o[7]);
}

// ---------------- segmented mean-pool (sorted batch) + fc, no atomics ----------
__global__ __launch_bounds__(128) void k_poolfc(const float* __restrict__ h3,
                                                const int* __restrict__ gstart,
                                                const float* __restrict__ W,
                                                const float* __restrict__ b,
                                                float* __restrict__ out) {
    int g = blockIdx.x;
    int t = threadIdx.x;  // 128
    int s0 = gstart[g], s1 = gstart[g + 1];
    int c = t & 63, half = t >> 6;
    float acc = 0.f;
    for (int r = s0 + half; r < s1; r += 2) acc += h3[(size_t)r * 64 + c];
    __shared__ float p2[128];
    __shared__ float p[64];
    p2[t] = acc;
    __syncthreads();
    if (t < 64) {
        float cntf = (float)(s1 - s0);
        p[t] = (p2[t] + p2[t + 64]) / fmaxf(cntf, 1.f);
    }
    __syncthreads();
    float o = b[t];
#pragma unroll
    for (int k = 0; k < 64; ++k) o = fmaf(p[k], W[k * 128 + t], o);
    out[g * 128 + t] = o;
}

extern "C" void kernel_launch(void* const* d_in, const int* in_sizes, int n_in,
                              void* d_out, int out_size, void* d_ws, size_t ws_size,
                              hipStream_t stream) {
    const float* x     = (const float*)d_in[0];
    const int*   ei    = (const int*)d_in[1];
    const int*   batch = (const int*)d_in[2];
    const float* W1    = (const float*)d_in[3];
    const float* as1   = (const float*)d_in[4];
    const float* ad1   = (const float*)d_in[5];
    const float* b1    = (const float*)d_in[6];
    const float* W2    = (const float*)d_in[7];
    const float* as2   = (const float*)d_in[8];
    const float* ad2   = (const float*)d_in[9];
    const float* b2    = (const float*)d_in[10];
    const float* W3    = (const float*)d_in[11];
    const float* as3   = (const float*)d_in[12];
    const float* ad3   = (const float*)d_in[13];
    const float* b3    = (const float*)d_in[14];
    const float* Wfc   = (const float*)d_in[15];
    const float* bfc   = (const float*)d_in[16];
    float* out = (float*)d_out;

    char* ws = (char*)d_ws;
    size_t off = 0;
    auto alloc = [&](size_t bytes) -> void* {
        void* p = ws + off;
        off += (bytes + 255) & ~(size_t)255;
        return p;
    };
    __half* Hf = (__half*)alloc((size_t)HEADS * N_NODES * 64 * 2);  // [head][node][64]
    __half* Hf3 = (__half*)alloc((size_t)N_NODES * 64 * 2);
    float* h3 = (float*)alloc((size_t)N_NODES * 64 * 4);
    unsigned short* Ah = (unsigned short*)alloc((size_t)MB_TILES * 16 * 4096 * 2);
    unsigned short* Al = (unsigned short*)alloc((size_t)MB_TILES * 16 * 4096 * 2);
    unsigned short* Wh1 = (unsigned short*)alloc((size_t)131072 * 2);
    unsigned short* Wl1 = (unsigned short*)alloc((size_t)131072 * 2);
    unsigned short* Wh2 = (unsigned short*)alloc((size_t)262144 * 2);
    unsigned short* Wl2 = (unsigned short*)alloc((size_t)262144 * 2);
    unsigned short* Wh3 = (unsigned short*)alloc((size_t)32768 * 2);
    unsigned short* Wl3 = (unsigned short*)alloc((size_t)32768 * 2);
    float* asb   = (float*)alloc((size_t)HEADS * N_NODES * 4);  // [head][node]
    float* adb   = (float*)alloc((size_t)HEADS * N_NODES * 4);
    int*   offs  = (int*)alloc((N_NODES + 1) * 4);
    int*   deg   = (int*)alloc(N_NODES * 4);   // reused as scatter cursor
    int*   csrc  = (int*)alloc((size_t)N_EDGES_SL * 4);
    int*   bsum  = (int*)alloc(NB_SCAN * 4);
    int*   bbase = (int*)alloc(NB_SCAN * 4);
    int*   gstart= (int*)alloc((NGRAPH + 1) * 4);

    hipMemsetAsync(deg, 0, N_NODES * 4, stream);

    // pack everything + graph bounds (depends only on inputs)
    k_packall<<<PACKALL_BLOCKS, 256, 0, stream>>>(x, W1, W2, W3, batch, Ah, Al,
                                                  Wh1, Wl1, Wh2, Wl2, Wh3, Wl3, gstart);
    // CSR build: count -> 3-phase parallel scan -> scatter
    k_count<<<(N_EDGES + 255) / 256, 256, 0, stream>>>(ei, deg);
    k_bsum<<<NB_SCAN, 256, 0, stream>>>(deg, bsum);
    k_bscan<<<1, 128, 0, stream>>>(bsum, bbase, offs + N_NODES);
    k_offs<<<NB_SCAN, 256, 0, stream>>>(deg, bbase, offs, deg);
    k_scatter<<<(N_EDGES_SL + 255) / 256, 256, 0, stream>>>(ei, deg, csrc);

    // ---- conv1: K=256 (KB=8) ----
    k_gemm8<8><<<dim3(MB_TILES, 4), 256, 0, stream>>>(Ah, Al, Wh1, Wl1, as1, ad1, Hf, asb, adb, N_NODES);
    k_agg8<<<2048, 256, 0, stream>>>(Hf, asb, adb, offs, csrc, b1, Ah, Al);

    // ---- conv2: K=512 (KB=16) ----
    k_gemm8<16><<<dim3(MB_TILES, 4), 256, 0, stream>>>(Ah, Al, Wh2, Wl2, as2, ad2, Hf, asb, adb, N_NODES);
    k_agg8<<<2048, 256, 0, stream>>>(Hf, asb, adb, offs, csrc, b2, Ah, Al);

    // ---- conv3: K=512 (KB=16), fused alpha epilogue ----
    k_gemm1<16><<<MB_TILES, 256, 0, stream>>>(Ah, Al, Wh3, Wl3, as3, ad3, Hf3, asb, adb, N_NODES);
    k_agg1<<<940, 256, 0, stream>>>(Hf3, asb, adb, offs, csrc, b3, h3);

    // ---- segmented mean-pool + fc ----
    k_poolfc<<<NGRAPH, 128, 0, stream>>>(h3, gstart, Wfc, bfc, out);
}

// Round 14
// 385.032 us; speedup vs baseline: 3.2520x; 1.1331x over previous
//
#include <hip/hip_runtime.h>
#include <hip/hip_fp16.h>
#include <math.h>

#define N_NODES 30000
#define N_EDGES 480000
#define N_EDGES_SL (N_EDGES + N_NODES)
#define DIM_IN 256
#define F1 512   // HEADS*HID
#define HEADS 8
#define NGRAPH 512
#define NEG 0.2f
#define MB_TILES 235  // ceil(30000/128)
#define NB_SCAN 118   // ceil(30000/256)

typedef __attribute__((ext_vector_type(8))) short short8;
typedef __attribute__((ext_vector_type(8))) _Float16 half8;
typedef __attribute__((ext_vector_type(4))) float f32x4;

__device__ __forceinline__ float lrelu(float x) { return fmaxf(x, NEG * x); }  // NEG in (0,1)
__device__ __forceinline__ float elu_(float x) { return x > 0.f ? x : __expf(x) - 1.f; }

// async global->LDS, 16B per lane
__device__ __forceinline__ void glds16(const unsigned short* g, unsigned short* l) {
    __builtin_amdgcn_global_load_lds(
        (const __attribute__((address_space(1))) unsigned int*)g,
        (__attribute__((address_space(3))) unsigned int*)l, 16, 0, 0);
}

// ---------------- CSR build ----------------
__global__ void k_count(const int* __restrict__ ei, int* __restrict__ deg) {
    int i = blockIdx.x * blockDim.x + threadIdx.x;
    if (i < N_EDGES) atomicAdd(&deg[ei[N_EDGES + i]], 1);
}

// 3-phase parallel scan (R10-measured)
__global__ __launch_bounds__(256) void k_bsum(const int* __restrict__ deg,
                                              int* __restrict__ bsum) {
    int i = blockIdx.x * 256 + threadIdx.x;
    int v = (i < N_NODES) ? deg[i] + 1 : 0;  // +1: self-loop
#pragma unroll
    for (int off = 1; off < 64; off <<= 1) v += __shfl_xor(v, off);
    __shared__ int ws[4];
    if ((threadIdx.x & 63) == 0) ws[threadIdx.x >> 6] = v;
    __syncthreads();
    if (threadIdx.x == 0) bsum[blockIdx.x] = ws[0] + ws[1] + ws[2] + ws[3];
}

__global__ __launch_bounds__(128) void k_bscan(const int* __restrict__ bsum,
                                               int* __restrict__ bbase,
                                               int* __restrict__ offsN) {
    __shared__ int p[128];
    int t = threadIdx.x;
    int v = (t < NB_SCAN) ? bsum[t] : 0;
    p[t] = v;
    __syncthreads();
    for (int off = 1; off < 128; off <<= 1) {
        int x = (t >= off) ? p[t - off] : 0;
        __syncthreads();
        p[t] += x;
        __syncthreads();
    }
    if (t < NB_SCAN) bbase[t] = p[t] - v;  // exclusive
    if (t == 127) *offsN = p[127];         // grand total -> offs[N_NODES]
}

__global__ __launch_bounds__(256) void k_offs(const int* __restrict__ deg,
                                              const int* __restrict__ bbase,
                                              int* __restrict__ offs,
                                              int* __restrict__ cursor) {
    int b = blockIdx.x, t = threadIdx.x;
    int i = b * 256 + t;
    int v = (i < N_NODES) ? deg[i] + 1 : 0;  // read BEFORE cursor write (aliases deg)
    __shared__ int p[256];
    p[t] = v;
    __syncthreads();
    for (int off = 1; off < 256; off <<= 1) {
        int x = (t >= off) ? p[t - off] : 0;
        __syncthreads();
        p[t] += x;
        __syncthreads();
    }
    if (i < N_NODES) {
        int excl = bbase[b] + p[t] - v;
        offs[i] = excl;
        cursor[i] = excl;
    }
}

__global__ void k_scatter(const int* __restrict__ ei, int* __restrict__ cursor,
                          int* __restrict__ csrc) {
    int i = blockIdx.x * blockDim.x + threadIdx.x;
    if (i >= N_EDGES_SL) return;
    int s, d;
    if (i < N_EDGES) { s = ei[i]; d = ei[N_EDGES + i]; }
    else { s = d = i - N_EDGES; }
    int p = atomicAdd(&cursor[d], 1);
    csrc[p] = s;
}

// ---------------- merged pack (fp16) + bounds ----------------
__device__ __forceinline__ void d_packA(int t, const float* __restrict__ A,
                                        unsigned short* __restrict__ out,
                                        int M, int K) {
    int KB = K >> 5;
    int k8 = t & 3;
    int ml = (t >> 2) & 127;
    int tmp = t >> 9;
    int kb = tmp % KB;
    int mb = tmp / KB;
    int m = mb * 128 + ml;
    int k0 = kb * 32 + k8 * 8;
    float v[8] = {0.f, 0.f, 0.f, 0.f, 0.f, 0.f, 0.f, 0.f};
    if (m < M) {
        float4 p0 = *(const float4*)(A + (size_t)m * K + k0);
        float4 p1 = *(const float4*)(A + (size_t)m * K + k0 + 4);
        v[0] = p0.x; v[1] = p0.y; v[2] = p0.z; v[3] = p0.w;
        v[4] = p1.x; v[5] = p1.y; v[6] = p1.z; v[7] = p1.w;
    }
    unsigned short h[8];
#pragma unroll
    for (int j = 0; j < 8; ++j) h[j] = __half_as_ushort(__float2half(v[j]));
    *(short8*)(out + (size_t)t * 8) = *(short8*)h;
}

__device__ __forceinline__ void d_packW(int t, const float* __restrict__ W,
                                        unsigned short* __restrict__ out,
                                        int K, int Nn, int BN, int LB) {
    int KB = K >> 5;
    int k8 = t & 3;
    int tmp = t >> 2;
    int nl = tmp & (BN - 1);
    int tmp2 = tmp >> LB;
    int kb = tmp2 % KB;
    int nb = tmp2 / KB;
    int n = nb * BN + nl;
    int k0 = kb * 32 + k8 * 8;
    unsigned short h[8];
#pragma unroll
    for (int j = 0; j < 8; ++j)
        h[j] = __half_as_ushort(__float2half(W[(size_t)(k0 + j) * Nn + n]));
    *(short8*)(out + (size_t)t * 8) = *(short8*)h;
}

#define PB_A 3760
#define PB_W1 64
#define PB_W2 128
#define PB_W3 16
__global__ __launch_bounds__(256) void k_packall(
        const float* __restrict__ x, const float* __restrict__ W1,
        const float* __restrict__ W2, const float* __restrict__ W3,
        const int* __restrict__ batch,
        unsigned short* __restrict__ Ah,
        unsigned short* __restrict__ Wh1, unsigned short* __restrict__ Wh2,
        unsigned short* __restrict__ Wh3, int* __restrict__ gstart) {
    int b = blockIdx.x, tid = threadIdx.x;
    if (b < PB_A) {
        d_packA(b * 256 + tid, x, Ah, N_NODES, DIM_IN);
    } else if (b < PB_A + PB_W1) {
        d_packW((b - PB_A) * 256 + tid, W1, Wh1, DIM_IN, F1, 128, 7);
    } else if (b < PB_A + PB_W1 + PB_W2) {
        d_packW((b - PB_A - PB_W1) * 256 + tid, W2, Wh2, F1, F1, 128, 7);
    } else if (b < PB_A + PB_W1 + PB_W2 + PB_W3) {
        d_packW((b - PB_A - PB_W1 - PB_W2) * 256 + tid, W3, Wh3, F1, 64, 64, 6);
    } else {
        int bb = b - (PB_A + PB_W1 + PB_W2 + PB_W3);
        int i = bb * 256 + tid;
        if (i >= N_NODES) return;
        int bt = batch[i];
        int pb = (i == 0) ? -1 : batch[i - 1];
        for (int g = pb + 1; g <= bt; ++g) gstart[g] = i;
        if (i == N_NODES - 1)
            for (int g = bt + 1; g <= NGRAPH; ++g) gstart[g] = N_NODES;
    }
}
#define PACKALL_BLOCKS (PB_A + PB_W1 + PB_W2 + PB_W3 + 118)

// ---------------- fp16 MFMA GEMM, 8-head conv (Nn=512, BN=128, NF=4) ----------
// Single-product fp16 (error ~= fp16 H storage already accepted; 1/3 the MFMA of
// split-bf16). Fused epilogue: H fp16 head-split + alphas head-split [head][node].
template <int KB>
__global__ __launch_bounds__(256) void k_gemm8(const unsigned short* __restrict__ Ah,
                                               const unsigned short* __restrict__ Bh,
                                               const float* __restrict__ a_src,
                                               const float* __restrict__ a_dst,
                                               __half* __restrict__ Hf,
                                               float* __restrict__ as_,
                                               float* __restrict__ ad_,
                                               int M) {
    __shared__ unsigned short sA[4096], sB[4096];
    const int tid = threadIdx.x, lane = tid & 63, wave = tid >> 6;
    const int mb = blockIdx.x, nb = blockIdx.y;
    const int wm = (wave >> 1) * 64;
    const int wn = (wave & 1) * 64;
    const int fr = lane & 15, quad = lane >> 4;

    const unsigned short* pA = Ah + (size_t)mb * KB * 4096;
    const unsigned short* pB = Bh + (size_t)nb * KB * 4096;

    f32x4 acc[4][4];
#pragma unroll
    for (int i = 0; i < 4; ++i)
#pragma unroll
        for (int j = 0; j < 4; ++j) acc[i][j] = {0.f, 0.f, 0.f, 0.f};

    for (int kb = 0; kb < KB; ++kb) {
        const unsigned short* a_g = pA + kb * 4096;
        const unsigned short* b_g = pB + kb * 4096;
#pragma unroll
        for (int s = 0; s < 2; ++s) {
            int sg = wave * 2 + s;
            glds16(a_g + sg * 512 + lane * 8, &sA[sg * 512]);
            glds16(b_g + sg * 512 + lane * 8, &sB[sg * 512]);
        }
        __syncthreads();

        half8 af[4], bf[4];
#pragma unroll
        for (int f = 0; f < 4; ++f) {
            int m = wm + f * 16 + fr;
            af[f] = *(const half8*)&sA[m * 32 + quad * 8];
            int n = wn + f * 16 + fr;
            bf[f] = *(const half8*)&sB[n * 32 + quad * 8];
        }
#pragma unroll
        for (int i = 0; i < 4; ++i)
#pragma unroll
            for (int j = 0; j < 4; ++j)
                acc[i][j] = __builtin_amdgcn_mfma_f32_16x16x32_f16(af[i], bf[j], acc[i][j], 0, 0, 0);
        __syncthreads();
    }
    // epilogue; C/D layout: col=lane&15, row=quad*4+reg
    const int head = (nb * 128 + wn) >> 6;  // wave's 64 cols = one head
    float avs[4], avd[4];
#pragma unroll
    for (int j = 0; j < 4; ++j) {
        avs[j] = a_src[head * 64 + j * 16 + fr];
        avd[j] = a_dst[head * 64 + j * 16 + fr];
    }
    __half* Hh = Hf + (size_t)head * N_NODES * 64;
#pragma unroll
    for (int i = 0; i < 4; ++i) {
#pragma unroll
        for (int r = 0; r < 4; ++r) {
            int row = mb * 128 + wm + i * 16 + quad * 4 + r;
            bool ok = row < M;
            float vs = 0.f, vd = 0.f;
#pragma unroll
            for (int j = 0; j < 4; ++j) {
                float c = acc[i][j][r];
                vs = fmaf(c, avs[j], vs);
                vd = fmaf(c, avd[j], vd);
                if (ok) Hh[(size_t)row * 64 + j * 16 + fr] = __float2half(c);
            }
#pragma unroll
            for (int off = 1; off < 16; off <<= 1) {
                vs += __shfl_xor(vs, off);
                vd += __shfl_xor(vd, off);
            }
            if (ok && fr == 0) {
                as_[head * N_NODES + row] = vs;
                ad_[head * N_NODES + row] = vd;
            }
        }
    }
}

// ---------------- conv3 GEMM (Nn=64), fp16, fused alpha projections ----------
template <int KB>
__global__ __launch_bounds__(256) void k_gemm1(const unsigned short* __restrict__ Ah,
                                               const unsigned short* __restrict__ Bh,
                                               const float* __restrict__ a_src,
                                               const float* __restrict__ a_dst,
                                               __half* __restrict__ C,
                                               float* __restrict__ as_,
                                               float* __restrict__ ad_,
                                               int M) {
    __shared__ unsigned short sA[4096], sB[2048];
    const int tid = threadIdx.x, lane = tid & 63, wave = tid >> 6;
    const int mb = blockIdx.x;
    const int wm = (wave >> 1) * 64;
    const int wn = (wave & 1) * 32;
    const int fr = lane & 15, quad = lane >> 4;

    const unsigned short* pA = Ah + (size_t)mb * KB * 4096;

    f32x4 acc[4][2];
#pragma unroll
    for (int i = 0; i < 4; ++i)
#pragma unroll
        for (int j = 0; j < 2; ++j) acc[i][j] = {0.f, 0.f, 0.f, 0.f};

    for (int kb = 0; kb < KB; ++kb) {
        const unsigned short* a_g = pA + kb * 4096;
        const unsigned short* b_g = Bh + kb * 2048;
#pragma unroll
        for (int s = 0; s < 2; ++s) {
            int sg = wave * 2 + s;
            glds16(a_g + sg * 512 + lane * 8, &sA[sg * 512]);
        }
        glds16(b_g + wave * 512 + lane * 8, &sB[wave * 512]);
        __syncthreads();

        half8 af[4], bf[2];
#pragma unroll
        for (int f = 0; f < 4; ++f) {
            int m = wm + f * 16 + fr;
            af[f] = *(const half8*)&sA[m * 32 + quad * 8];
        }
#pragma unroll
        for (int f = 0; f < 2; ++f) {
            int n = wn + f * 16 + fr;
            bf[f] = *(const half8*)&sB[n * 32 + quad * 8];
        }
#pragma unroll
        for (int i = 0; i < 4; ++i)
#pragma unroll
            for (int j = 0; j < 2; ++j)
                acc[i][j] = __builtin_amdgcn_mfma_f32_16x16x32_f16(af[i], bf[j], acc[i][j], 0, 0, 0);
        __syncthreads();
    }
    // epilogue: Hf3 write + fused alpha projections (a_src/a_dst are 64-wide)
    float avs[2], avd[2];
#pragma unroll
    for (int j = 0; j < 2; ++j) {
        avs[j] = a_src[wn + j * 16 + fr];
        avd[j] = a_dst[wn + j * 16 + fr];
    }
    float* ps = (float*)sA;  // reused post-loop (all waves past final sync)
    float* pd = (float*)sB;
#pragma unroll
    for (int i = 0; i < 4; ++i) {
#pragma unroll
        for (int r = 0; r < 4; ++r) {
            int rl = wm + i * 16 + quad * 4 + r;  // 0..127 row in block
            int row = mb * 128 + rl;
            bool ok = row < M;
            float vs = 0.f, vd = 0.f;
#pragma unroll
            for (int j = 0; j < 2; ++j) {
                float c = acc[i][j][r];
                vs = fmaf(c, avs[j], vs);
                vd = fmaf(c, avd[j], vd);
                if (ok) C[(size_t)row * 64 + wn + j * 16 + fr] = __float2half(c);
            }
#pragma unroll
            for (int off = 1; off < 16; off <<= 1) {
                vs += __shfl_xor(vs, off);
                vd += __shfl_xor(vd, off);
            }
            if (fr == 0) {
                ps[wave * 64 + (rl & 63)] = vs;
                pd[wave * 64 + (rl & 63)] = vd;
            }
        }
    }
    __syncthreads();
    if (tid < 128) {
        int row = mb * 128 + tid;
        if (row < M) {
            int wp = (tid >> 6) * 2;  // rows 0-63: waves 0+1; rows 64-127: waves 2+3
            as_[row] = ps[wp * 64 + (tid & 63)] + ps[(wp + 1) * 64 + (tid & 63)];
            ad_[row] = pd[wp * 64 + (tid & 63)] + pd[(wp + 1) * 64 + (tid & 63)];
        }
    }
}

// process one gathered edge: w*H[src] into 8-channel accumulator (v_fma_mix path)
__device__ __forceinline__ void edge_fma(float w, uint4 u, float* a) {
    const _Float16* hp = (const _Float16*)&u;
#pragma unroll
    for (int k = 0; k < 8; ++k) a[k] = fmaf(w, (float)hp[k], a[k]);
}

// ---------------- softmax-aggregate (8 heads), head-split, XCD-affine --------------
// One wave = 8 dsts x 1 head; lane owns (dst = lane>>3, 8 ch = lane&7). Single pass,
// inline exp, STATIC octet stride. Epilogue packs fp16 A-tile (single buffer).
// head = blockIdx&7 pins head to XCD (2048 co-resident blocks).
__global__ __launch_bounds__(256) void k_agg8(const __half* __restrict__ Hf,
                                              const float* __restrict__ as_,
                                              const float* __restrict__ ad_,
                                              const int* __restrict__ offs,
                                              const int* __restrict__ csrc,
                                              const float* __restrict__ bias,
                                              unsigned short* __restrict__ outA) {
    const int head = blockIdx.x & 7;
    const int bg = blockIdx.x >> 3;  // 0..255
    const int wave = threadIdx.x >> 6, lane = threadIdx.x & 63;
    const int g = lane >> 3, cl = lane & 7;
    const unsigned coff = (unsigned)(cl * 8);
    const __half* Hh = Hf + (size_t)head * N_NODES * 64;
    const float* ash = as_ + head * N_NODES;
    const float* adh = ad_ + head * N_NODES;
    float bia[8];
#pragma unroll
    for (int j = 0; j < 8; ++j) bia[j] = bias[head * 64 + cl * 8 + j];

    // N_NODES % 8 == 0 -> every octet fully valid
    for (int d0 = (bg * 4 + wave) * 8; d0 < N_NODES; d0 += 8192) {
        int dst = d0 + g;
        int beg = offs[dst], end = offs[dst + 1];
        float adv = adh[dst];
        const int* cp = csrc + beg;
        int deg = end - beg;
        float s = 0.f;
        float a[8] = {0.f, 0.f, 0.f, 0.f, 0.f, 0.f, 0.f, 0.f};
        float b[8] = {0.f, 0.f, 0.f, 0.f, 0.f, 0.f, 0.f, 0.f};
        int loc = 0;
        for (; loc + 3 < deg; loc += 4) {
            unsigned s0 = (unsigned)cp[loc], s1 = (unsigned)cp[loc + 1];
            unsigned s2 = (unsigned)cp[loc + 2], s3 = (unsigned)cp[loc + 3];
            float e0 = ash[s0], e1 = ash[s1], e2 = ash[s2], e3 = ash[s3];
            uint4 u0 = *(const uint4*)(Hh + s0 * 64u + coff);
            uint4 u1 = *(const uint4*)(Hh + s1 * 64u + coff);
            uint4 u2 = *(const uint4*)(Hh + s2 * 64u + coff);
            uint4 u3 = *(const uint4*)(Hh + s3 * 64u + coff);
            float w0 = __expf(lrelu(e0 + adv));
            float w1 = __expf(lrelu(e1 + adv));
            float w2 = __expf(lrelu(e2 + adv));
            float w3 = __expf(lrelu(e3 + adv));
            s += (w0 + w1) + (w2 + w3);
            edge_fma(w0, u0, a);
            edge_fma(w1, u1, b);
            edge_fma(w2, u2, a);
            edge_fma(w3, u3, b);
        }
        for (; loc < deg; ++loc) {
            unsigned s0 = (unsigned)cp[loc];
            float w = __expf(lrelu(ash[s0] + adv));
            uint4 u = *(const uint4*)(Hh + s0 * 64u + coff);
            s += w;
            edge_fma(w, u, a);
        }
        float inv = 1.f / s;
        unsigned short h[8];
#pragma unroll
        for (int k = 0; k < 8; ++k)
            h[k] = __half_as_ushort(__float2half(elu_((a[k] + b[k]) * inv + bia[k])));
        // packed fp16 A-tile write: global ch c0 = head*64 + cl*8
        int c0 = head * 64 + cl * 8;
        int kb = c0 >> 5, kl = c0 & 31;
        int mb = dst >> 7, ml = dst & 127;
        size_t oo = (((size_t)(mb * 16 + kb) * 128 + ml) * 32 + kl);
        *(short8*)(outA + oo) = *(short8*)h;
    }
}

// single-pass, 4-deep pipeline; writes h3 [node][64] fp32
__global__ __launch_bounds__(256) void k_agg1(const __half* __restrict__ Hf,
                                              const float* __restrict__ as_,
                                              const float* __restrict__ ad_,
                                              const int* __restrict__ offs,
                                              const int* __restrict__ csrc,
                                              const float* __restrict__ bias,
                                              float* __restrict__ h3) {
    const int wave = threadIdx.x >> 6, lane = threadIdx.x & 63;
    const int g = lane >> 3, cl = lane & 7;
    const unsigned coff = (unsigned)(cl * 8);
    int d0 = (blockIdx.x * 4 + wave) * 8;  // grid 940 -> 3760 octets >= 3750
    if (d0 >= N_NODES) return;
    int dst = d0 + g;
    float bia[8];
#pragma unroll
    for (int j = 0; j < 8; ++j) bia[j] = bias[cl * 8 + j];
    int beg = offs[dst], end = offs[dst + 1];
    float adv = ad_[dst];
    const int* cp = csrc + beg;
    int deg = end - beg;
    float s = 0.f;
    float a[8] = {0.f, 0.f, 0.f, 0.f, 0.f, 0.f, 0.f, 0.f};
    float b[8] = {0.f, 0.f, 0.f, 0.f, 0.f, 0.f, 0.f, 0.f};
    int loc = 0;
    for (; loc + 3 < deg; loc += 4) {
        unsigned s0 = (unsigned)cp[loc], s1 = (unsigned)cp[loc + 1];
        unsigned s2 = (unsigned)cp[loc + 2], s3 = (unsigned)cp[loc + 3];
        float e0 = as_[s0], e1 = as_[s1], e2 = as_[s2], e3 = as_[s3];
        uint4 u0 = *(const uint4*)(Hf + s0 * 64u + coff);
        uint4 u1 = *(const uint4*)(Hf + s1 * 64u + coff);
        uint4 u2 = *(const uint4*)(Hf + s2 * 64u + coff);
        uint4 u3 = *(const uint4*)(Hf + s3 * 64u + coff);
        float w0 = __expf(lrelu(e0 + adv));
        float w1 = __expf(lrelu(e1 + adv));
        float w2 = __expf(lrelu(e2 + adv));
        float w3 = __expf(lrelu(e3 + adv));
        s += (w0 + w1) + (w2 + w3);
        edge_fma(w0, u0, a);
        edge_fma(w1, u1, b);
        edge_fma(w2, u2, a);
        edge_fma(w3, u3, b);
    }
    for (; loc < deg; ++loc) {
        unsigned s0 = (unsigned)cp[loc];
        float w = __expf(lrelu(as_[s0] + adv));
        uint4 u = *(const uint4*)(Hf + s0 * 64u + coff);
        s += w;
        edge_fma(w, u, a);
    }
    float inv = 1.f / s;
    float o[8];
#pragma unroll
    for (int k = 0; k < 8; ++k) o[k] = elu_((a[k] + b[k]) * inv + bia[k]);
    float* op = h3 + (size_t)dst * 64 + cl * 8;
    *(float4*)op = make_float4(o[0], o[1], o[2], o[3]);
    *(float4*)(op + 4) = make_float4(o[4], o[5], o[6], o[7]);
}

// ---------------- segmented mean-pool (sorted batch) + fc, no atomics ----------
__global__ __launch_bounds__(128) void k_poolfc(const float* __restrict__ h3,
                                                const int* __restrict__ gstart,
                                                const float* __restrict__ W,
                                                const float* __restrict__ b,
                                                float* __restrict__ out) {
    int g = blockIdx.x;
    int t = threadIdx.x;  // 128
    int s0 = gstart[g], s1 = gstart[g + 1];
    int c = t & 63, half = t >> 6;
    float acc = 0.f;
    for (int r = s0 + half; r < s1; r += 2) acc += h3[(size_t)r * 64 + c];
    __shared__ float p2[128];
    __shared__ float p[64];
    p2[t] = acc;
    __syncthreads();
    if (t < 64) {
        float cntf = (float)(s1 - s0);
        p[t] = (p2[t] + p2[t + 64]) / fmaxf(cntf, 1.f);
    }
    __syncthreads();
    float o = b[t];
#pragma unroll
    for (int k = 0; k < 64; ++k) o = fmaf(p[k], W[k * 128 + t], o);
    out[g * 128 + t] = o;
}

extern "C" void kernel_launch(void* const* d_in, const int* in_sizes, int n_in,
                              void* d_out, int out_size, void* d_ws, size_t ws_size,
                              hipStream_t stream) {
    const float* x     = (const float*)d_in[0];
    const int*   ei    = (const int*)d_in[1];
    const int*   batch = (const int*)d_in[2];
    const float* W1    = (const float*)d_in[3];
    const float* as1   = (const float*)d_in[4];
    const float* ad1   = (const float*)d_in[5];
    const float* b1    = (const float*)d_in[6];
    const float* W2    = (const float*)d_in[7];
    const float* as2   = (const float*)d_in[8];
    const float* ad2   = (const float*)d_in[9];
    const float* b2    = (const float*)d_in[10];
    const float* W3    = (const float*)d_in[11];
    const float* as3   = (const float*)d_in[12];
    const float* ad3   = (const float*)d_in[13];
    const float* b3    = (const float*)d_in[14];
    const float* Wfc   = (const float*)d_in[15];
    const float* bfc   = (const float*)d_in[16];
    float* out = (float*)d_out;

    char* ws = (char*)d_ws;
    size_t off = 0;
    auto alloc = [&](size_t bytes) -> void* {
        void* p = ws + off;
        off += (bytes + 255) & ~(size_t)255;
        return p;
    };
    __half* Hf = (__half*)alloc((size_t)HEADS * N_NODES * 64 * 2);  // [head][node][64]
    __half* Hf3 = (__half*)alloc((size_t)N_NODES * 64 * 2);
    float* h3 = (float*)alloc((size_t)N_NODES * 64 * 4);
    unsigned short* Ah = (unsigned short*)alloc((size_t)MB_TILES * 16 * 4096 * 2);  // fp16 A-tiles
    unsigned short* Wh1 = (unsigned short*)alloc((size_t)131072 * 2);
    unsigned short* Wh2 = (unsigned short*)alloc((size_t)262144 * 2);
    unsigned short* Wh3 = (unsigned short*)alloc((size_t)32768 * 2);
    float* asb   = (float*)alloc((size_t)HEADS * N_NODES * 4);  // [head][node]
    float* adb   = (float*)alloc((size_t)HEADS * N_NODES * 4);
    int*   offs  = (int*)alloc((N_NODES + 1) * 4);
    int*   deg   = (int*)alloc(N_NODES * 4);   // reused as scatter cursor
    int*   csrc  = (int*)alloc((size_t)N_EDGES_SL * 4);
    int*   bsum  = (int*)alloc(NB_SCAN * 4);
    int*   bbase = (int*)alloc(NB_SCAN * 4);
    int*   gstart= (int*)alloc((NGRAPH + 1) * 4);

    hipMemsetAsync(deg, 0, N_NODES * 4, stream);

    // pack everything (fp16) + graph bounds
    k_packall<<<PACKALL_BLOCKS, 256, 0, stream>>>(x, W1, W2, W3, batch, Ah,
                                                  Wh1, Wh2, Wh3, gstart);
    // CSR build: count -> 3-phase parallel scan -> scatter
    k_count<<<(N_EDGES + 255) / 256, 256, 0, stream>>>(ei, deg);
    k_bsum<<<NB_SCAN, 256, 0, stream>>>(deg, bsum);
    k_bscan<<<1, 128, 0, stream>>>(bsum, bbase, offs + N_NODES);
    k_offs<<<NB_SCAN, 256, 0, stream>>>(deg, bbase, offs, deg);
    k_scatter<<<(N_EDGES_SL + 255) / 256, 256, 0, stream>>>(ei, deg, csrc);

    // ---- conv1: K=256 (KB=8) ----
    k_gemm8<8><<<dim3(MB_TILES, 4), 256, 0, stream>>>(Ah, Wh1, as1, ad1, Hf, asb, adb, N_NODES);
    k_agg8<<<2048, 256, 0, stream>>>(Hf, asb, adb, offs, csrc, b1, Ah);

    // ---- conv2: K=512 (KB=16) ----
    k_gemm8<16><<<dim3(MB_TILES, 4), 256, 0, stream>>>(Ah, Wh2, as2, ad2, Hf, asb, adb, N_NODES);
    k_agg8<<<2048, 256, 0, stream>>>(Hf, asb, adb, offs, csrc, b2, Ah);

    // ---- conv3: K=512 (KB=16), fused alpha epilogue ----
    k_gemm1<16><<<MB_TILES, 256, 0, stream>>>(Ah, Wh3, as3, ad3, Hf3, asb, adb, N_NODES);
    k_agg1<<<940, 256, 0, stream>>>(Hf3, asb, adb, offs, csrc, b3, h3);

    // ---- segmented mean-pool + fc ----
    k_poolfc<<<NGRAPH, 128, 0, stream>>>(h3, gstart, Wfc, bfc, out);
}

// Round 15
// 383.462 us; speedup vs baseline: 3.2653x; 1.0041x over previous
//
#include <hip/hip_runtime.h>
#include <hip/hip_fp16.h>
#include <math.h>

#define N_NODES 30000
#define N_EDGES 480000
#define N_EDGES_SL (N_EDGES + N_NODES)
#define DIM_IN 256
#define F1 512   // HEADS*HID
#define HEADS 8
#define NGRAPH 512
#define NEG 0.2f
#define MB_TILES 235  // ceil(30000/128)
#define NB_SCAN 118   // ceil(30000/256)

typedef __attribute__((ext_vector_type(8))) short short8;
typedef __attribute__((ext_vector_type(8))) _Float16 half8;
typedef __attribute__((ext_vector_type(4))) float f32x4;

__device__ __forceinline__ float lrelu(float x) { return fmaxf(x, NEG * x); }  // NEG in (0,1)
__device__ __forceinline__ float elu_(float x) { return x > 0.f ? x : __expf(x) - 1.f; }

// async global->LDS, 16B per lane
__device__ __forceinline__ void glds16(const unsigned short* g, unsigned short* l) {
    __builtin_amdgcn_global_load_lds(
        (const __attribute__((address_space(1))) unsigned int*)g,
        (__attribute__((address_space(3))) unsigned int*)l, 16, 0, 0);
}

// 3-phase parallel scan (R10-measured)
__global__ __launch_bounds__(256) void k_bsum(const int* __restrict__ deg,
                                              int* __restrict__ bsum) {
    int i = blockIdx.x * 256 + threadIdx.x;
    int v = (i < N_NODES) ? deg[i] + 1 : 0;  // +1: self-loop
#pragma unroll
    for (int off = 1; off < 64; off <<= 1) v += __shfl_xor(v, off);
    __shared__ int ws[4];
    if ((threadIdx.x & 63) == 0) ws[threadIdx.x >> 6] = v;
    __syncthreads();
    if (threadIdx.x == 0) bsum[blockIdx.x] = ws[0] + ws[1] + ws[2] + ws[3];
}

__global__ __launch_bounds__(128) void k_bscan(const int* __restrict__ bsum,
                                               int* __restrict__ bbase,
                                               int* __restrict__ offsN) {
    __shared__ int p[128];
    int t = threadIdx.x;
    int v = (t < NB_SCAN) ? bsum[t] : 0;
    p[t] = v;
    __syncthreads();
    for (int off = 1; off < 128; off <<= 1) {
        int x = (t >= off) ? p[t - off] : 0;
        __syncthreads();
        p[t] += x;
        __syncthreads();
    }
    if (t < NB_SCAN) bbase[t] = p[t] - v;  // exclusive
    if (t == 127) *offsN = p[127];         // grand total -> offs[N_NODES]
}

__global__ __launch_bounds__(256) void k_offs(const int* __restrict__ deg,
                                              const int* __restrict__ bbase,
                                              int* __restrict__ offs,
                                              int* __restrict__ cursor) {
    int b = blockIdx.x, t = threadIdx.x;
    int i = b * 256 + t;
    int v = (i < N_NODES) ? deg[i] + 1 : 0;  // read BEFORE cursor write (aliases deg)
    __shared__ int p[256];
    p[t] = v;
    __syncthreads();
    for (int off = 1; off < 256; off <<= 1) {
        int x = (t >= off) ? p[t - off] : 0;
        __syncthreads();
        p[t] += x;
        __syncthreads();
    }
    if (i < N_NODES) {
        int excl = bbase[b] + p[t] - v;
        offs[i] = excl;
        cursor[i] = excl;
    }
}

__global__ void k_scatter(const int* __restrict__ ei, int* __restrict__ cursor,
                          int* __restrict__ csrc) {
    int i = blockIdx.x * blockDim.x + threadIdx.x;
    if (i >= N_EDGES_SL) return;
    int s, d;
    if (i < N_EDGES) { s = ei[i]; d = ei[N_EDGES + i]; }
    else { s = d = i - N_EDGES; }
    int p = atomicAdd(&cursor[d], 1);
    csrc[p] = s;
}

// ---------------- merged pack (fp16) + bounds + degree count ----------------
__device__ __forceinline__ void d_packA(int t, const float* __restrict__ A,
                                        unsigned short* __restrict__ out,
                                        int M, int K) {
    int KB = K >> 5;
    int k8 = t & 3;
    int ml = (t >> 2) & 127;
    int tmp = t >> 9;
    int kb = tmp % KB;
    int mb = tmp / KB;
    int m = mb * 128 + ml;
    int k0 = kb * 32 + k8 * 8;
    float v[8] = {0.f, 0.f, 0.f, 0.f, 0.f, 0.f, 0.f, 0.f};
    if (m < M) {
        float4 p0 = *(const float4*)(A + (size_t)m * K + k0);
        float4 p1 = *(const float4*)(A + (size_t)m * K + k0 + 4);
        v[0] = p0.x; v[1] = p0.y; v[2] = p0.z; v[3] = p0.w;
        v[4] = p1.x; v[5] = p1.y; v[6] = p1.z; v[7] = p1.w;
    }
    unsigned short h[8];
#pragma unroll
    for (int j = 0; j < 8; ++j) h[j] = __half_as_ushort(__float2half(v[j]));
    *(short8*)(out + (size_t)t * 8) = *(short8*)h;
}

__device__ __forceinline__ void d_packW(int t, const float* __restrict__ W,
                                        unsigned short* __restrict__ out,
                                        int K, int Nn, int BN, int LB) {
    int KB = K >> 5;
    int k8 = t & 3;
    int tmp = t >> 2;
    int nl = tmp & (BN - 1);
    int tmp2 = tmp >> LB;
    int kb = tmp2 % KB;
    int nb = tmp2 / KB;
    int n = nb * BN + nl;
    int k0 = kb * 32 + k8 * 8;
    unsigned short h[8];
#pragma unroll
    for (int j = 0; j < 8; ++j)
        h[j] = __half_as_ushort(__float2half(W[(size_t)(k0 + j) * Nn + n]));
    *(short8*)(out + (size_t)t * 8) = *(short8*)h;
}

#define PB_A 3760
#define PB_W1 64
#define PB_W2 128
#define PB_W3 16
#define PB_B 118
#define PB_CNT 1875  // ceil(480000/256)
__global__ __launch_bounds__(256) void k_packall(
        const float* __restrict__ x, const float* __restrict__ W1,
        const float* __restrict__ W2, const float* __restrict__ W3,
        const int* __restrict__ batch, const int* __restrict__ ei,
        unsigned short* __restrict__ Ah,
        unsigned short* __restrict__ Wh1, unsigned short* __restrict__ Wh2,
        unsigned short* __restrict__ Wh3, int* __restrict__ gstart,
        int* __restrict__ deg) {
    int b = blockIdx.x, tid = threadIdx.x;
    if (b < PB_A) {
        d_packA(b * 256 + tid, x, Ah, N_NODES, DIM_IN);
    } else if (b < PB_A + PB_W1) {
        d_packW((b - PB_A) * 256 + tid, W1, Wh1, DIM_IN, F1, 128, 7);
    } else if (b < PB_A + PB_W1 + PB_W2) {
        d_packW((b - PB_A - PB_W1) * 256 + tid, W2, Wh2, F1, F1, 128, 7);
    } else if (b < PB_A + PB_W1 + PB_W2 + PB_W3) {
        d_packW((b - PB_A - PB_W1 - PB_W2) * 256 + tid, W3, Wh3, F1, 64, 64, 6);
    } else if (b < PB_A + PB_W1 + PB_W2 + PB_W3 + PB_B) {
        int bb = b - (PB_A + PB_W1 + PB_W2 + PB_W3);
        int i = bb * 256 + tid;
        if (i >= N_NODES) return;
        int bt = batch[i];
        int pb = (i == 0) ? -1 : batch[i - 1];
        for (int g = pb + 1; g <= bt; ++g) gstart[g] = i;
        if (i == N_NODES - 1)
            for (int g = bt + 1; g <= NGRAPH; ++g) gstart[g] = N_NODES;
    } else {
        int i = (b - (PB_A + PB_W1 + PB_W2 + PB_W3 + PB_B)) * 256 + tid;
        if (i < N_EDGES) atomicAdd(&deg[ei[N_EDGES + i]], 1);
    }
}
#define PACKALL_BLOCKS (PB_A + PB_W1 + PB_W2 + PB_W3 + PB_B + PB_CNT)

// ---------------- fp16 MFMA GEMM, 8-head conv (Nn=512, BN=128, NF=4) ----------
template <int KB>
__global__ __launch_bounds__(256) void k_gemm8(const unsigned short* __restrict__ Ah,
                                               const unsigned short* __restrict__ Bh,
                                               const float* __restrict__ a_src,
                                               const float* __restrict__ a_dst,
                                               __half* __restrict__ Hf,
                                               float* __restrict__ as_,
                                               float* __restrict__ ad_,
                                               int M) {
    __shared__ unsigned short sA[4096], sB[4096];
    const int tid = threadIdx.x, lane = tid & 63, wave = tid >> 6;
    const int mb = blockIdx.x, nb = blockIdx.y;
    const int wm = (wave >> 1) * 64;
    const int wn = (wave & 1) * 64;
    const int fr = lane & 15, quad = lane >> 4;

    const unsigned short* pA = Ah + (size_t)mb * KB * 4096;
    const unsigned short* pB = Bh + (size_t)nb * KB * 4096;

    f32x4 acc[4][4];
#pragma unroll
    for (int i = 0; i < 4; ++i)
#pragma unroll
        for (int j = 0; j < 4; ++j) acc[i][j] = {0.f, 0.f, 0.f, 0.f};

    for (int kb = 0; kb < KB; ++kb) {
        const unsigned short* a_g = pA + kb * 4096;
        const unsigned short* b_g = pB + kb * 4096;
#pragma unroll
        for (int s = 0; s < 2; ++s) {
            int sg = wave * 2 + s;
            glds16(a_g + sg * 512 + lane * 8, &sA[sg * 512]);
            glds16(b_g + sg * 512 + lane * 8, &sB[sg * 512]);
        }
        __syncthreads();

        half8 af[4], bf[4];
#pragma unroll
        for (int f = 0; f < 4; ++f) {
            int m = wm + f * 16 + fr;
            af[f] = *(const half8*)&sA[m * 32 + quad * 8];
            int n = wn + f * 16 + fr;
            bf[f] = *(const half8*)&sB[n * 32 + quad * 8];
        }
#pragma unroll
        for (int i = 0; i < 4; ++i)
#pragma unroll
            for (int j = 0; j < 4; ++j)
                acc[i][j] = __builtin_amdgcn_mfma_f32_16x16x32_f16(af[i], bf[j], acc[i][j], 0, 0, 0);
        __syncthreads();
    }
    // epilogue; C/D layout: col=lane&15, row=quad*4+reg
    const int head = (nb * 128 + wn) >> 6;  // wave's 64 cols = one head
    float avs[4], avd[4];
#pragma unroll
    for (int j = 0; j < 4; ++j) {
        avs[j] = a_src[head * 64 + j * 16 + fr];
        avd[j] = a_dst[head * 64 + j * 16 + fr];
    }
    __half* Hh = Hf + (size_t)head * N_NODES * 64;
#pragma unroll
    for (int i = 0; i < 4; ++i) {
#pragma unroll
        for (int r = 0; r < 4; ++r) {
            int row = mb * 128 + wm + i * 16 + quad * 4 + r;
            bool ok = row < M;
            float vs = 0.f, vd = 0.f;
#pragma unroll
            for (int j = 0; j < 4; ++j) {
                float c = acc[i][j][r];
                vs = fmaf(c, avs[j], vs);
                vd = fmaf(c, avd[j], vd);
                if (ok) Hh[(size_t)row * 64 + j * 16 + fr] = __float2half(c);
            }
#pragma unroll
            for (int off = 1; off < 16; off <<= 1) {
                vs += __shfl_xor(vs, off);
                vd += __shfl_xor(vd, off);
            }
            if (ok && fr == 0) {
                as_[head * N_NODES + row] = vs;
                ad_[head * N_NODES + row] = vd;
            }
        }
    }
}

// ---------------- conv3 GEMM (Nn=64), fp16, fused alpha projections ----------
template <int KB>
__global__ __launch_bounds__(256) void k_gemm1(const unsigned short* __restrict__ Ah,
                                               const unsigned short* __restrict__ Bh,
                                               const float* __restrict__ a_src,
                                               const float* __restrict__ a_dst,
                                               __half* __restrict__ C,
                                               float* __restrict__ as_,
                                               float* __restrict__ ad_,
                                               int M) {
    __shared__ unsigned short sA[4096], sB[2048];
    const int tid = threadIdx.x, lane = tid & 63, wave = tid >> 6;
    const int mb = blockIdx.x;
    const int wm = (wave >> 1) * 64;
    const int wn = (wave & 1) * 32;
    const int fr = lane & 15, quad = lane >> 4;

    const unsigned short* pA = Ah + (size_t)mb * KB * 4096;

    f32x4 acc[4][2];
#pragma unroll
    for (int i = 0; i < 4; ++i)
#pragma unroll
        for (int j = 0; j < 2; ++j) acc[i][j] = {0.f, 0.f, 0.f, 0.f};

    for (int kb = 0; kb < KB; ++kb) {
        const unsigned short* a_g = pA + kb * 4096;
        const unsigned short* b_g = Bh + kb * 2048;
#pragma unroll
        for (int s = 0; s < 2; ++s) {
            int sg = wave * 2 + s;
            glds16(a_g + sg * 512 + lane * 8, &sA[sg * 512]);
        }
        glds16(b_g + wave * 512 + lane * 8, &sB[wave * 512]);
        __syncthreads();

        half8 af[4], bf[2];
#pragma unroll
        for (int f = 0; f < 4; ++f) {
            int m = wm + f * 16 + fr;
            af[f] = *(const half8*)&sA[m * 32 + quad * 8];
        }
#pragma unroll
        for (int f = 0; f < 2; ++f) {
            int n = wn + f * 16 + fr;
            bf[f] = *(const half8*)&sB[n * 32 + quad * 8];
        }
#pragma unroll
        for (int i = 0; i < 4; ++i)
#pragma unroll
            for (int j = 0; j < 2; ++j)
                acc[i][j] = __builtin_amdgcn_mfma_f32_16x16x32_f16(af[i], bf[j], acc[i][j], 0, 0, 0);
        __syncthreads();
    }
    // epilogue: Hf3 write + fused alpha projections (a_src/a_dst are 64-wide)
    float avs[2], avd[2];
#pragma unroll
    for (int j = 0; j < 2; ++j) {
        avs[j] = a_src[wn + j * 16 + fr];
        avd[j] = a_dst[wn + j * 16 + fr];
    }
    float* ps = (float*)sA;  // reused post-loop (all waves past final sync)
    float* pd = (float*)sB;
#pragma unroll
    for (int i = 0; i < 4; ++i) {
#pragma unroll
        for (int r = 0; r < 4; ++r) {
            int rl = wm + i * 16 + quad * 4 + r;  // 0..127 row in block
            int row = mb * 128 + rl;
            bool ok = row < M;
            float vs = 0.f, vd = 0.f;
#pragma unroll
            for (int j = 0; j < 2; ++j) {
                float c = acc[i][j][r];
                vs = fmaf(c, avs[j], vs);
                vd = fmaf(c, avd[j], vd);
                if (ok) C[(size_t)row * 64 + wn + j * 16 + fr] = __float2half(c);
            }
#pragma unroll
            for (int off = 1; off < 16; off <<= 1) {
                vs += __shfl_xor(vs, off);
                vd += __shfl_xor(vd, off);
            }
            if (fr == 0) {
                ps[wave * 64 + (rl & 63)] = vs;
                pd[wave * 64 + (rl & 63)] = vd;
            }
        }
    }
    __syncthreads();
    if (tid < 128) {
        int row = mb * 128 + tid;
        if (row < M) {
            int wp = (tid >> 6) * 2;  // rows 0-63: waves 0+1; rows 64-127: waves 2+3
            as_[row] = ps[wp * 64 + (tid & 63)] + ps[(wp + 1) * 64 + (tid & 63)];
            ad_[row] = pd[wp * 64 + (tid & 63)] + pd[(wp + 1) * 64 + (tid & 63)];
        }
    }
}

// process one gathered edge: w*H[src] into 8-channel accumulator (v_fma_mix path)
__device__ __forceinline__ void edge_fma(float w, uint4 u, float* a) {
    const _Float16* hp = (const _Float16*)&u;
#pragma unroll
    for (int k = 0; k < 8; ++k) a[k] = fmaf(w, (float)hp[k], a[k]);
}

// ---------------- softmax-aggregate (8 heads), head-split, XCD-affine --------------
// One wave = 8 dsts x 1 head. Single pass, inline exp, static octet stride.
// Index PREFETCH: next quad of csrc loads issued while current quad's gathers are
// in flight (breaks the index->gather serial chain; csrc padded so over-read safe).
__global__ __launch_bounds__(256) void k_agg8(const __half* __restrict__ Hf,
                                              const float* __restrict__ as_,
                                              const float* __restrict__ ad_,
                                              const int* __restrict__ offs,
                                              const int* __restrict__ csrc,
                                              const float* __restrict__ bias,
                                              unsigned short* __restrict__ outA) {
    const int head = blockIdx.x & 7;
    const int bg = blockIdx.x >> 3;  // 0..255
    const int wave = threadIdx.x >> 6, lane = threadIdx.x & 63;
    const int g = lane >> 3, cl = lane & 7;
    const unsigned coff = (unsigned)(cl * 8);
    const __half* Hh = Hf + (size_t)head * N_NODES * 64;
    const float* ash = as_ + head * N_NODES;
    const float* adh = ad_ + head * N_NODES;
    float bia[8];
#pragma unroll
    for (int j = 0; j < 8; ++j) bia[j] = bias[head * 64 + cl * 8 + j];

    for (int d0 = (bg * 4 + wave) * 8; d0 < N_NODES; d0 += 8192) {
        int dst = d0 + g;
        int beg = offs[dst], end = offs[dst + 1];
        float adv = adh[dst];
        const int* cp = csrc + beg;
        int deg = end - beg;
        float s = 0.f;
        float a[8] = {0.f, 0.f, 0.f, 0.f, 0.f, 0.f, 0.f, 0.f};
        float b[8] = {0.f, 0.f, 0.f, 0.f, 0.f, 0.f, 0.f, 0.f};
        int loc = 0;
        unsigned i0 = 0, i1 = 0, i2 = 0, i3 = 0;
        if (deg >= 4) {
            i0 = (unsigned)cp[0]; i1 = (unsigned)cp[1];
            i2 = (unsigned)cp[2]; i3 = (unsigned)cp[3];
        }
        for (; loc + 3 < deg; loc += 4) {
            float e0 = ash[i0], e1 = ash[i1], e2 = ash[i2], e3 = ash[i3];
            uint4 u0 = *(const uint4*)(Hh + i0 * 64u + coff);
            uint4 u1 = *(const uint4*)(Hh + i1 * 64u + coff);
            uint4 u2 = *(const uint4*)(Hh + i2 * 64u + coff);
            uint4 u3 = *(const uint4*)(Hh + i3 * 64u + coff);
            // prefetch next quad (padded buffer; values used only if loop continues)
            i0 = (unsigned)cp[loc + 4]; i1 = (unsigned)cp[loc + 5];
            i2 = (unsigned)cp[loc + 6]; i3 = (unsigned)cp[loc + 7];
            float w0 = __expf(lrelu(e0 + adv));
            float w1 = __expf(lrelu(e1 + adv));
            float w2 = __expf(lrelu(e2 + adv));
            float w3 = __expf(lrelu(e3 + adv));
            s += (w0 + w1) + (w2 + w3);
            edge_fma(w0, u0, a);
            edge_fma(w1, u1, b);
            edge_fma(w2, u2, a);
            edge_fma(w3, u3, b);
        }
        for (; loc < deg; ++loc) {
            unsigned s0 = (unsigned)cp[loc];
            float w = __expf(lrelu(ash[s0] + adv));
            uint4 u = *(const uint4*)(Hh + s0 * 64u + coff);
            s += w;
            edge_fma(w, u, a);
        }
        float inv = 1.f / s;
        unsigned short h[8];
#pragma unroll
        for (int k = 0; k < 8; ++k)
            h[k] = __half_as_ushort(__float2half(elu_((a[k] + b[k]) * inv + bia[k])));
        // packed fp16 A-tile write: global ch c0 = head*64 + cl*8
        int c0 = head * 64 + cl * 8;
        int kb = c0 >> 5, kl = c0 & 31;
        int mb = dst >> 7, ml = dst & 127;
        size_t oo = (((size_t)(mb * 16 + kb) * 128 + ml) * 32 + kl);
        *(short8*)(outA + oo) = *(short8*)h;
    }
}

// single-pass, index-prefetch pipeline; writes h3 [node][64] fp32
__global__ __launch_bounds__(256) void k_agg1(const __half* __restrict__ Hf,
                                              const float* __restrict__ as_,
                                              const float* __restrict__ ad_,
                                              const int* __restrict__ offs,
                                              const int* __restrict__ csrc,
                                              const float* __restrict__ bias,
                                              float* __restrict__ h3) {
    const int wave = threadIdx.x >> 6, lane = threadIdx.x & 63;
    const int g = lane >> 3, cl = lane & 7;
    const unsigned coff = (unsigned)(cl * 8);
    int d0 = (blockIdx.x * 4 + wave) * 8;  // grid 940 -> 3760 octets >= 3750
    if (d0 >= N_NODES) return;
    int dst = d0 + g;
    float bia[8];
#pragma unroll
    for (int j = 0; j < 8; ++j) bia[j] = bias[cl * 8 + j];
    int beg = offs[dst], end = offs[dst + 1];
    float adv = ad_[dst];
    const int* cp = csrc + beg;
    int deg = end - beg;
    float s = 0.f;
    float a[8] = {0.f, 0.f, 0.f, 0.f, 0.f, 0.f, 0.f, 0.f};
    float b[8] = {0.f, 0.f, 0.f, 0.f, 0.f, 0.f, 0.f, 0.f};
    int loc = 0;
    unsigned i0 = 0, i1 = 0, i2 = 0, i3 = 0;
    if (deg >= 4) {
        i0 = (unsigned)cp[0]; i1 = (unsigned)cp[1];
        i2 = (unsigned)cp[2]; i3 = (unsigned)cp[3];
    }
    for (; loc + 3 < deg; loc += 4) {
        float e0 = as_[i0], e1 = as_[i1], e2 = as_[i2], e3 = as_[i3];
        uint4 u0 = *(const uint4*)(Hf + i0 * 64u + coff);
        uint4 u1 = *(const uint4*)(Hf + i1 * 64u + coff);
        uint4 u2 = *(const uint4*)(Hf + i2 * 64u + coff);
        uint4 u3 = *(const uint4*)(Hf + i3 * 64u + coff);
        i0 = (unsigned)cp[loc + 4]; i1 = (unsigned)cp[loc + 5];
        i2 = (unsigned)cp[loc + 6]; i3 = (unsigned)cp[loc + 7];
        float w0 = __expf(lrelu(e0 + adv));
        float w1 = __expf(lrelu(e1 + adv));
        float w2 = __expf(lrelu(e2 + adv));
        float w3 = __expf(lrelu(e3 + adv));
        s += (w0 + w1) + (w2 + w3);
        edge_fma(w0, u0, a);
        edge_fma(w1, u1, b);
        edge_fma(w2, u2, a);
        edge_fma(w3, u3, b);
    }
    for (; loc < deg; ++loc) {
        unsigned s0 = (unsigned)cp[loc];
        float w = __expf(lrelu(as_[s0] + adv));
        uint4 u = *(const uint4*)(Hf + s0 * 64u + coff);
        s += w;
        edge_fma(w, u, a);
    }
    float inv = 1.f / s;
    float o[8];
#pragma unroll
    for (int k = 0; k < 8; ++k) o[k] = elu_((a[k] + b[k]) * inv + bia[k]);
    float* op = h3 + (size_t)dst * 64 + cl * 8;
    *(float4*)op = make_float4(o[0], o[1], o[2], o[3]);
    *(float4*)(op + 4) = make_float4(o[4], o[5], o[6], o[7]);
}

// ---------------- segmented mean-pool (sorted batch) + fc, no atomics ----------
__global__ __launch_bounds__(128) void k_poolfc(const float* __restrict__ h3,
                                                const int* __restrict__ gstart,
                                                const float* __restrict__ W,
                                                const float* __restrict__ b,
                                                float* __restrict__ out) {
    int g = blockIdx.x;
    int t = threadIdx.x;  // 128
    int s0 = gstart[g], s1 = gstart[g + 1];
    int c = t & 63, half = t >> 6;
    float acc = 0.f;
    for (int r = s0 + half; r < s1; r += 2) acc += h3[(size_t)r * 64 + c];
    __shared__ float p2[128];
    __shared__ float p[64];
    p2[t] = acc;
    __syncthreads();
    if (t < 64) {
        float cntf = (float)(s1 - s0);
        p[t] = (p2[t] + p2[t + 64]) / fmaxf(cntf, 1.f);
    }
    __syncthreads();
    float o = b[t];
#pragma unroll
    for (int k = 0; k < 64; ++k) o = fmaf(p[k], W[k * 128 + t], o);
    out[g * 128 + t] = o;
}

extern "C" void kernel_launch(void* const* d_in, const int* in_sizes, int n_in,
                              void* d_out, int out_size, void* d_ws, size_t ws_size,
                              hipStream_t stream) {
    const float* x     = (const float*)d_in[0];
    const int*   ei    = (const int*)d_in[1];
    const int*   batch = (const int*)d_in[2];
    const float* W1    = (const float*)d_in[3];
    const float* as1   = (const float*)d_in[4];
    const float* ad1   = (const float*)d_in[5];
    const float* b1    = (const float*)d_in[6];
    const float* W2    = (const float*)d_in[7];
    const float* as2   = (const float*)d_in[8];
    const float* ad2   = (const float*)d_in[9];
    const float* b2    = (const float*)d_in[10];
    const float* W3    = (const float*)d_in[11];
    const float* as3   = (const float*)d_in[12];
    const float* ad3   = (const float*)d_in[13];
    const float* b3    = (const float*)d_in[14];
    const float* Wfc   = (const float*)d_in[15];
    const float* bfc   = (const float*)d_in[16];
    float* out = (float*)d_out;

    char* ws = (char*)d_ws;
    size_t off = 0;
    auto alloc = [&](size_t bytes) -> void* {
        void* p = ws + off;
        off += (bytes + 255) & ~(size_t)255;
        return p;
    };
    __half* Hf = (__half*)alloc((size_t)HEADS * N_NODES * 64 * 2);  // [head][node][64]
    __half* Hf3 = (__half*)alloc((size_t)N_NODES * 64 * 2);
    float* h3 = (float*)alloc((size_t)N_NODES * 64 * 4);
    unsigned short* Ah = (unsigned short*)alloc((size_t)MB_TILES * 16 * 4096 * 2);  // fp16 A-tiles
    unsigned short* Wh1 = (unsigned short*)alloc((size_t)131072 * 2);
    unsigned short* Wh2 = (unsigned short*)alloc((size_t)262144 * 2);
    unsigned short* Wh3 = (unsigned short*)alloc((size_t)32768 * 2);
    float* asb   = (float*)alloc((size_t)HEADS * N_NODES * 4);  // [head][node]
    float* adb   = (float*)alloc((size_t)HEADS * N_NODES * 4);
    int*   offs  = (int*)alloc((N_NODES + 1) * 4);
    int*   deg   = (int*)alloc(N_NODES * 4);   // reused as scatter cursor
    int*   csrc  = (int*)alloc((size_t)N_EDGES_SL * 4 + 32);  // +32B: prefetch pad
    int*   bsum  = (int*)alloc(NB_SCAN * 4);
    int*   bbase = (int*)alloc(NB_SCAN * 4);
    int*   gstart= (int*)alloc((NGRAPH + 1) * 4);

    hipMemsetAsync(deg, 0, N_NODES * 4, stream);

    // pack (fp16) + graph bounds + degree count (all input-only deps)
    k_packall<<<PACKALL_BLOCKS, 256, 0, stream>>>(x, W1, W2, W3, batch, ei, Ah,
                                                  Wh1, Wh2, Wh3, gstart, deg);
    // CSR: 3-phase parallel scan -> scatter
    k_bsum<<<NB_SCAN, 256, 0, stream>>>(deg, bsum);
    k_bscan<<<1, 128, 0, stream>>>(bsum, bbase, offs + N_NODES);
    k_offs<<<NB_SCAN, 256, 0, stream>>>(deg, bbase, offs, deg);
    k_scatter<<<(N_EDGES_SL + 255) / 256, 256, 0, stream>>>(ei, deg, csrc);

    // ---- conv1: K=256 (KB=8) ----
    k_gemm8<8><<<dim3(MB_TILES, 4), 256, 0, stream>>>(Ah, Wh1, as1, ad1, Hf, asb, adb, N_NODES);
    k_agg8<<<2048, 256, 0, stream>>>(Hf, asb, adb, offs, csrc, b1, Ah);

    // ---- conv2: K=512 (KB=16) ----
    k_gemm8<16><<<dim3(MB_TILES, 4), 256, 0, stream>>>(Ah, Wh2, as2, ad2, Hf, asb, adb, N_NODES);
    k_agg8<<<2048, 256, 0, stream>>>(Hf, asb, adb, offs, csrc, b2, Ah);

    // ---- conv3: K=512 (KB=16), fused alpha epilogue ----
    k_gemm1<16><<<MB_TILES, 256, 0, stream>>>(Ah, Wh3, as3, ad3, Hf3, asb, adb, N_NODES);
    k_agg1<<<940, 256, 0, stream>>>(Hf3, asb, adb, offs, csrc, b3, h3);

    // ---- segmented mean-pool + fc ----
    k_poolfc<<<NGRAPH, 128, 0, stream>>>(h3, gstart, Wfc, bfc, out);
}